// Round 8
// baseline (598.733 us; speedup 1.0000x reference)
//
#include <hip/hip_runtime.h>
#include <hip/hip_bf16.h>

typedef __attribute__((ext_vector_type(8))) short bf16x8;
typedef __attribute__((ext_vector_type(4))) float f32x4;
typedef __attribute__((ext_vector_type(4))) int i32x4;
typedef __attribute__((ext_vector_type(4))) unsigned short u16x4;
typedef __attribute__((ext_vector_type(8))) unsigned short u16x8;

#define LDS_STRIDE 72   // reg-staged kernel only

__device__ __forceinline__ unsigned short f2bf(float f) {
    __hip_bfloat16 h = __float2bfloat16(f);
    unsigned short u; __builtin_memcpy(&u, &h, 2); return u;
}
__device__ __forceinline__ float bf2f(unsigned short u) {
    union { unsigned u; float f; } v; v.u = ((unsigned)u) << 16; return v.f;
}
__device__ __forceinline__ float fast_sigmoid(float x) { return 1.f / (1.f + __expf(-x)); }
__device__ __forceinline__ float fast_tanh(float x)    { return 1.f - 2.f / (__expf(2.f * x) + 1.f); }

#define GLOAD_LDS16(gp, lp) __builtin_amdgcn_global_load_lds( \
    (const __attribute__((address_space(1))) void*)(gp), \
    (__attribute__((address_space(3))) void*)(lp), 16, 0, 0)

// ===========================================================================
// e-GEMM v4 "gemm_bg": 128x128 tile, 4 waves (2x2, wave-tile 64x64), BK=64.
// A staged via global_load_lds into 32KB dbuf LDS (XOR-swizzled, r3-verified);
// B fragments read DIRECTLY from global (WiB = 2MB, L2-resident; 32KB/K-tile
// slab is L1-hot). LDS halved + VGPR<=168 -> 3-4 blocks/CU: cross-block TLP
// hides the per-block vmcnt/barrier drain (m114 mechanism) instead of the
// fragile intra-block phase schedules of r5-r7.
// Epilogue: epart[(b*256+t)*16 + nb*2+wc] = sum_n tanh(acc+hproj)*wscore.
// ===========================================================================
__global__ __launch_bounds__(256, 3)
void gemm_bg(const unsigned short* __restrict__ Ag, const unsigned short* __restrict__ Bg,
             const float* __restrict__ hproj, const float* __restrict__ wscore,
             float* __restrict__ epart)
{
    const int tid = threadIdx.x;
    const int lane = tid & 63, wid = tid >> 6;
    const int fr = lane & 15, fg = lane >> 4;
    const int wr = wid >> 1, wc = wid & 1;      // 2x2 wave grid, 64x64 tiles

    // bijective XCD remap: grid 4096 (512 mb x 8 nb), nb-minor per XCD ->
    // A-panels and all of B shared within an XCD's L2.
    const int cpx = (int)gridDim.x >> 3;        // 512
    const int bp_ = ((int)blockIdx.x & 7) * cpx + ((int)blockIdx.x >> 3);
    const int mb = bp_ >> 3, nb = bp_ & 7;
    const int m0 = mb << 7, n0 = nb << 7;

    __shared__ unsigned short AL[2][128][64];   // 32 KB dbuf, A only

    const int g_row = lane >> 3;
    const int scol = ((lane & 7) ^ g_row) << 3; // inverse-swizzled global col
    const int swzr = (fr & 7) << 3;             // ds_read swizzle

    // B fragment base pointers (advance by immediate kt*128B in unrolled loop)
    const unsigned short* bp[4];
#pragma unroll
    for (int ni = 0; ni < 4; ++ni)
        bp[ni] = Bg + (size_t)(n0 + wc * 64 + ni * 16 + fr) * 1024 + fg * 8;

    f32x4 acc[4][4];
#pragma unroll
    for (int i = 0; i < 4; ++i)
#pragma unroll
        for (int j = 0; j < 4; ++j) acc[i][j] = (f32x4){0.f, 0.f, 0.f, 0.f};

    auto stage = [&](int buf, int kt) {
        const size_t kof = (size_t)kt * 64 + scol;
#pragma unroll
        for (int i = 0; i < 4; ++i) {
            const int row = wid * 32 + i * 8;
            GLOAD_LDS16(Ag + (size_t)(m0 + row + g_row) * 1024 + kof, &AL[buf][row][0]);
        }
    };

    stage(0, 0);
    __syncthreads();

#pragma unroll
    for (int kt = 0; kt < 16; ++kt) {
        const int cur = kt & 1;
        if (kt + 1 < 16) stage(cur ^ 1, kt + 1);
#pragma unroll
        for (int ks = 0; ks < 2; ++ks) {
            const int col = (ks * 32 + fg * 8) ^ swzr;
            bf16x8 av[4], bv[4];
#pragma unroll
            for (int ni = 0; ni < 4; ++ni)
                bv[ni] = *(const bf16x8*)(bp[ni] + kt * 64 + ks * 32);
#pragma unroll
            for (int mi = 0; mi < 4; ++mi)
                av[mi] = *(const bf16x8*)&AL[cur][wr * 64 + mi * 16 + fr][col];
#pragma unroll
            for (int mi = 0; mi < 4; ++mi)
#pragma unroll
                for (int ni = 0; ni < 4; ++ni)
                    acc[mi][ni] = __builtin_amdgcn_mfma_f32_16x16x32_bf16(av[mi], bv[ni], acc[mi][ni], 0, 0, 0);
        }
        __syncthreads();
    }

    // epilogue: fused tanh-dot-wscore partials (r4-verified layout, pw=16)
    float wsv[4];
#pragma unroll
    for (int ni = 0; ni < 4; ++ni) wsv[ni] = wscore[n0 + wc * 64 + ni * 16 + fr];
#pragma unroll
    for (int mi = 0; mi < 4; ++mi)
#pragma unroll
        for (int r = 0; r < 4; ++r) {
            const int m = m0 + wr * 64 + mi * 16 + fg * 4 + r;
            const int bb = m & 255, tt = m >> 8;
            const float* hp = hproj + (size_t)bb * 1024 + n0 + wc * 64 + fr;
            float s = 0.f;
#pragma unroll
            for (int ni = 0; ni < 4; ++ni)
                s += fast_tanh(acc[mi][ni][r] + hp[ni * 16]) * wsv[ni];
            s += __shfl_xor(s, 1); s += __shfl_xor(s, 2);
            s += __shfl_xor(s, 4); s += __shfl_xor(s, 8);
            if (fr == 0) epart[((size_t)bb * 256 + tt) * 16 + nb * 2 + wc] = s;
        }
}

// ---------------------------------------------------------------------------
// Fused h-projection GEMM: C = h0 @ [W_h2h ; W_hh]^T + [b_h2h ; b_hh]
// grid 64 = 2 mb x 32 nb (nb<8 -> hproj region, else gh region).
// ---------------------------------------------------------------------------
__global__ __launch_bounds__(256, 2)
void gemm_h2(const float* __restrict__ h0,
             const float* __restrict__ Wh2h, const float* __restrict__ Whh,
             const float* __restrict__ bh2h, const float* __restrict__ bhh,
             float* __restrict__ hproj, float* __restrict__ gh)
{
    const int mb = blockIdx.x & 1;
    const int nbg = blockIdx.x >> 1;            // 0..31
    const float* Bf; const float* bias; float* Cout; int Nst; int n0;
    if (nbg < 8) { Bf = Wh2h; bias = bh2h; Cout = hproj; Nst = 1024; n0 = nbg << 7; }
    else         { Bf = Whh;  bias = bhh;  Cout = gh;    Nst = 3072; n0 = (nbg - 8) << 7; }

    const int m0 = mb << 7;
    const int tid = threadIdx.x;
    const int lane = tid & 63, wid = tid >> 6;
    const int fr = lane & 15, fg = lane >> 4;
    const int srow = tid >> 1, shalf = (tid & 1) * 32;

    extern __shared__ char smem[];
    typedef unsigned short (*tile_t)[128][LDS_STRIDE];
    tile_t As = (tile_t)smem;
    tile_t Bs = (tile_t)(smem + 2 * 128 * LDS_STRIDE * 2);

    f32x4 acc[2][8];
#pragma unroll
    for (int i = 0; i < 2; ++i)
#pragma unroll
        for (int j = 0; j < 8; ++j) acc[i][j] = (f32x4){0.f, 0.f, 0.f, 0.f};

    float a_f[32], b_f[32];

    auto loadA = [&](int kt) {
        size_t base = (size_t)(m0 + srow) * 1024 + (size_t)kt * 64 + shalf;
#pragma unroll
        for (int j = 0; j < 8; ++j) *(f32x4*)&a_f[j * 4] = *(const f32x4*)(h0 + base + j * 4);
    };
    auto loadB = [&](int kt) {
        size_t base = (size_t)(n0 + srow) * 1024 + (size_t)kt * 64 + shalf;
#pragma unroll
        for (int j = 0; j < 8; ++j) *(f32x4*)&b_f[j * 4] = *(const f32x4*)(Bf + base + j * 4);
    };
    auto storeA = [&](int buf) {
        unsigned short t[32];
#pragma unroll
        for (int j = 0; j < 32; ++j) t[j] = f2bf(a_f[j]);
#pragma unroll
        for (int j = 0; j < 4; ++j) *(i32x4*)&As[buf][srow][shalf + j * 8] = *(i32x4*)&t[j * 8];
    };
    auto storeB = [&](int buf) {
        unsigned short t[32];
#pragma unroll
        for (int j = 0; j < 32; ++j) t[j] = f2bf(b_f[j]);
#pragma unroll
        for (int j = 0; j < 4; ++j) *(i32x4*)&Bs[buf][srow][shalf + j * 8] = *(i32x4*)&t[j * 8];
    };

    loadA(0); loadB(0);
    storeA(0); storeB(0);
    __syncthreads();

    for (int kt = 0; kt < 16; ++kt) {
        const int cur = kt & 1;
        if (kt + 1 < 16) { loadA(kt + 1); loadB(kt + 1); }
#pragma unroll
        for (int ks = 0; ks < 2; ++ks) {
            bf16x8 av[2], bv[8];
#pragma unroll
            for (int mi = 0; mi < 2; ++mi)
                av[mi] = *(const bf16x8*)&As[cur][wid * 32 + mi * 16 + fr][ks * 32 + fg * 8];
#pragma unroll
            for (int ni = 0; ni < 8; ++ni)
                bv[ni] = *(const bf16x8*)&Bs[cur][ni * 16 + fr][ks * 32 + fg * 8];
#pragma unroll
            for (int mi = 0; mi < 2; ++mi)
#pragma unroll
                for (int ni = 0; ni < 8; ++ni)
                    acc[mi][ni] = __builtin_amdgcn_mfma_f32_16x16x32_bf16(av[mi], bv[ni], acc[mi][ni], 0, 0, 0);
        }
        if (kt + 1 < 16) { storeA(cur ^ 1); storeB(cur ^ 1); }
        __syncthreads();
    }

#pragma unroll
    for (int mi = 0; mi < 2; ++mi)
#pragma unroll
        for (int r = 0; r < 4; ++r) {
            const int m = m0 + wid * 32 + mi * 16 + fg * 4 + r;
#pragma unroll
            for (int ni = 0; ni < 8; ++ni) {
                const int col = n0 + ni * 16 + fr;
                Cout[(size_t)m * Nst + col] = acc[mi][ni][r] + bias[col];
            }
        }
}

// ---------------------------------------------------------------------------
// Reg-staged GEMM — gi GEMM (EPI0), fallback e-GEMM (EPI1), logits (EPI2).
// ---------------------------------------------------------------------------
template<int EPI, bool ABF, bool BBF>
__global__ __launch_bounds__(256, 2)
void gemm_rs(const void* __restrict__ Agv, const void* __restrict__ Bgv,
             const float* __restrict__ bias, float* __restrict__ Cout,
             unsigned short* __restrict__ CoutB,
             const float* __restrict__ hproj, const float* __restrict__ wscore,
             float* __restrict__ epart, float* __restrict__ lsepart,
             int M, int N, int K)
{
    const int nbn = N >> 7;
    const int nmb = M >> 7;
    int mb, nb;
    if (EPI == 1) {
        int cpx = gridDim.x >> 3;
        int bp = (blockIdx.x & 7) * cpx + (blockIdx.x >> 3);
        mb = bp / nbn; nb = bp % nbn;
    } else {
        mb = blockIdx.x % nmb; nb = blockIdx.x / nmb;
    }
    const int m0 = mb << 7, n0 = nb << 7;
    const int tid = threadIdx.x;
    const int lane = tid & 63, wid = tid >> 6;
    const int fr = lane & 15, fg = lane >> 4;
    const int srow = tid >> 1, shalf = (tid & 1) * 32;

    extern __shared__ char smem[];
    typedef unsigned short (*tile_t)[128][LDS_STRIDE];
    tile_t As = (tile_t)smem;
    tile_t Bs = (tile_t)(smem + 2 * 128 * LDS_STRIDE * 2);

    const float* Af = (const float*)Agv;
    const unsigned short* Ab = (const unsigned short*)Agv;
    const float* Bf = (const float*)Bgv;
    const unsigned short* Bb = (const unsigned short*)Bgv;

    f32x4 acc[2][8];
#pragma unroll
    for (int i = 0; i < 2; ++i)
#pragma unroll
        for (int j = 0; j < 8; ++j) acc[i][j] = (f32x4){0.f, 0.f, 0.f, 0.f};

    float a_f[32]; unsigned short a_b[32];
    float b_f[32]; unsigned short b_b[32];

    auto loadA = [&](int kt) {
        size_t base = (size_t)(m0 + srow) * K + (size_t)kt * 64 + shalf;
        if (ABF) {
#pragma unroll
            for (int j = 0; j < 4; ++j) *(i32x4*)&a_b[j * 8] = *(const i32x4*)(Ab + base + j * 8);
        } else {
#pragma unroll
            for (int j = 0; j < 8; ++j) *(f32x4*)&a_f[j * 4] = *(const f32x4*)(Af + base + j * 4);
        }
    };
    auto loadB = [&](int kt) {
        size_t base = (size_t)(n0 + srow) * K + (size_t)kt * 64 + shalf;
        if (BBF) {
#pragma unroll
            for (int j = 0; j < 4; ++j) *(i32x4*)&b_b[j * 8] = *(const i32x4*)(Bb + base + j * 8);
        } else {
#pragma unroll
            for (int j = 0; j < 8; ++j) *(f32x4*)&b_f[j * 4] = *(const f32x4*)(Bf + base + j * 4);
        }
    };
    auto storeA = [&](int buf) {
        unsigned short tA[32];
        if (ABF) {
#pragma unroll
            for (int j = 0; j < 32; ++j) tA[j] = a_b[j];
        } else {
#pragma unroll
            for (int j = 0; j < 32; ++j) tA[j] = f2bf(a_f[j]);
        }
#pragma unroll
        for (int j = 0; j < 4; ++j) *(i32x4*)&As[buf][srow][shalf + j * 8] = *(i32x4*)&tA[j * 8];
    };
    auto storeB = [&](int buf) {
        unsigned short tB[32];
        if (BBF) {
#pragma unroll
            for (int j = 0; j < 32; ++j) tB[j] = b_b[j];
        } else {
#pragma unroll
            for (int j = 0; j < 32; ++j) tB[j] = f2bf(b_f[j]);
        }
#pragma unroll
        for (int j = 0; j < 4; ++j) *(i32x4*)&Bs[buf][srow][shalf + j * 8] = *(i32x4*)&tB[j * 8];
    };

    const int nkt = K >> 6;

    loadA(0); loadB(0);
    storeA(0); storeB(0);
    __syncthreads();

    for (int kt = 0; kt < nkt; ++kt) {
        const int cur = kt & 1;
        if (kt + 1 < nkt) { loadA(kt + 1); loadB(kt + 1); }
#pragma unroll
        for (int ks = 0; ks < 2; ++ks) {
            bf16x8 av[2], bv[8];
#pragma unroll
            for (int mi = 0; mi < 2; ++mi)
                av[mi] = *(const bf16x8*)&As[cur][wid * 32 + mi * 16 + fr][ks * 32 + fg * 8];
#pragma unroll
            for (int ni = 0; ni < 8; ++ni)
                bv[ni] = *(const bf16x8*)&Bs[cur][ni * 16 + fr][ks * 32 + fg * 8];
#pragma unroll
            for (int mi = 0; mi < 2; ++mi)
#pragma unroll
                for (int ni = 0; ni < 8; ++ni)
                    acc[mi][ni] = __builtin_amdgcn_mfma_f32_16x16x32_bf16(av[mi], bv[ni], acc[mi][ni], 0, 0, 0);
        }
        if (kt + 1 < nkt) { storeA(cur ^ 1); storeB(cur ^ 1); }
        __syncthreads();
    }

    if (EPI == 0) {
#pragma unroll
        for (int mi = 0; mi < 2; ++mi)
#pragma unroll
            for (int r = 0; r < 4; ++r) {
                const int m = m0 + wid * 32 + mi * 16 + fg * 4 + r;
#pragma unroll
                for (int ni = 0; ni < 8; ++ni) {
                    const int col = n0 + ni * 16 + fr;
                    Cout[(size_t)m * N + col] = acc[mi][ni][r] + bias[col];
                }
            }
    } else if (EPI == 1) {
        float wsv[8];
#pragma unroll
        for (int ni = 0; ni < 8; ++ni) wsv[ni] = wscore[n0 + ni * 16 + fr];
#pragma unroll
        for (int mi = 0; mi < 2; ++mi)
#pragma unroll
            for (int r = 0; r < 4; ++r) {
                const int m = m0 + wid * 32 + mi * 16 + fg * 4 + r;
                const int bb = m & 255, tt = m >> 8;
                const float* hp = hproj + (size_t)bb * 1024 + n0 + fr;
                float s = 0.f;
#pragma unroll
                for (int ni = 0; ni < 8; ++ni)
                    s += fast_tanh(acc[mi][ni][r] + hp[ni * 16]) * wsv[ni];
                s += __shfl_xor(s, 1); s += __shfl_xor(s, 2);
                s += __shfl_xor(s, 4); s += __shfl_xor(s, 8);
                if (fr == 0) epart[((size_t)bb * 256 + tt) * 8 + nb] = s;
            }
    } else {  // EPI 2: bf16 logits + (max,sumexp) partials
#pragma unroll
        for (int mi = 0; mi < 2; ++mi)
#pragma unroll
            for (int r = 0; r < 4; ++r) {
                const int m = m0 + wid * 32 + mi * 16 + fg * 4 + r;
                float vv[8];
                float mx = -3.4e38f;
#pragma unroll
                for (int ni = 0; ni < 8; ++ni) {
                    const int col = n0 + ni * 16 + fr;
                    vv[ni] = acc[mi][ni][r] + bias[col];
                    CoutB[(size_t)m * N + col] = f2bf(vv[ni]);
                    mx = fmaxf(mx, vv[ni]);
                }
                mx = fmaxf(mx, __shfl_xor(mx, 1));
                mx = fmaxf(mx, __shfl_xor(mx, 2));
                mx = fmaxf(mx, __shfl_xor(mx, 4));
                mx = fmaxf(mx, __shfl_xor(mx, 8));
                float se = 0.f;
#pragma unroll
                for (int ni = 0; ni < 8; ++ni) se += __expf(vv[ni] - mx);
                se += __shfl_xor(se, 1); se += __shfl_xor(se, 2);
                se += __shfl_xor(se, 4); se += __shfl_xor(se, 8);
                if (fr == 0) {
                    lsepart[((size_t)m * nbn + nb) * 2]     = mx;
                    lsepart[((size_t)m * nbn + nb) * 2 + 1] = se;
                }
            }
    }
}

// ---------------------------------------------------------------------------
// merged prep: enc f32->bf16 + W_i2h f32->bf16 + emb gather (grid-stride)
__global__ void prep_all(const float* __restrict__ enc, unsigned short* __restrict__ encB,
                         const float* __restrict__ Wi2h, unsigned short* __restrict__ WiB,
                         const float* __restrict__ emb, const int* __restrict__ tokens,
                         unsigned short* __restrict__ xB)
{
    const int ENC4 = 16777216, WI4 = 262144, EMB4 = 65536;
    const int total = ENC4 + WI4 + EMB4;
    for (int i = blockIdx.x * 256 + threadIdx.x; i < total; i += gridDim.x * 256) {
        f32x4 v; unsigned short* dst;
        if (i < ENC4) {
            v = *(const f32x4*)(enc + (size_t)i * 4);
            dst = encB + (size_t)i * 4;
        } else if (i < ENC4 + WI4) {
            int j = i - ENC4;
            v = *(const f32x4*)(Wi2h + (size_t)j * 4);
            dst = WiB + (size_t)j * 4;
        } else {
            int j = i - ENC4 - WI4;
            int b = j >> 8, h4 = j & 255;
            v = *(const f32x4*)(emb + (size_t)tokens[b] * 1024 + h4 * 4);
            dst = xB + (size_t)b * 2048 + 1024 + h4 * 4;
        }
        u16x4 o;
#pragma unroll
        for (int j = 0; j < 4; ++j) o[j] = f2bf(v[j]);
        *(u16x4*)dst = o;
    }
}

// fallback prep: W_i2h conv + emb gather only
__global__ void prep_kernel(const float* __restrict__ Wi2h, unsigned short* __restrict__ WiB,
                            const float* __restrict__ emb, const int* __restrict__ tokens,
                            unsigned short* __restrict__ xB)
{
    int i = blockIdx.x * 256 + threadIdx.x;
    if (i < 262144) {
        f32x4 v = *(const f32x4*)(Wi2h + (size_t)i * 4);
        u16x4 o;
#pragma unroll
        for (int j = 0; j < 4; ++j) o[j] = f2bf(v[j]);
        *(u16x4*)(WiB + (size_t)i * 4) = o;
    } else {
        int j = i - 262144;
        int b = j >> 8, h4 = j & 255;
        int tok = tokens[b];
        f32x4 v = *(const f32x4*)(emb + (size_t)tok * 1024 + h4 * 4);
        u16x4 o;
#pragma unroll
        for (int jj = 0; jj < 4; ++jj) o[jj] = f2bf(v[jj]);
        *(u16x4*)(xB + (size_t)b * 2048 + 1024 + h4 * 4) = o;
    }
}

// softmax over t per batch b; epart is [b][t][pw] partials
__global__ __launch_bounds__(256) void softmax_alpha(const float* __restrict__ epart,
                                                     float* __restrict__ alpha, int pw)
{
    const int b = blockIdx.x, t = threadIdx.x;
    const int lane = t & 63, w = t >> 6;
    const float* ep = epart + ((size_t)b * 256 + t) * pw;
    float s = 0.f;
    for (int j = 0; j < pw; ++j) s += ep[j];
    __shared__ float rmax[4], rsum[4];
    float mx = s;
#pragma unroll
    for (int d = 1; d < 64; d <<= 1) mx = fmaxf(mx, __shfl_xor(mx, d));
    if (lane == 0) rmax[w] = mx;
    __syncthreads();
    mx = fmaxf(fmaxf(rmax[0], rmax[1]), fmaxf(rmax[2], rmax[3]));
    float p = __expf(s - mx);
    float sm = p;
#pragma unroll
    for (int d = 1; d < 64; d <<= 1) sm += __shfl_xor(sm, d);
    if (lane == 0) rsum[w] = sm;
    __syncthreads();
    sm = rsum[0] + rsum[1] + rsum[2] + rsum[3];
    alpha[(size_t)b * 256 + t] = p / sm;
}

// context partials from bf16 enc
__global__ __launch_bounds__(128) void ctx_part_bf(const float* __restrict__ alpha,
                                                   const unsigned short* __restrict__ encB,
                                                   float* __restrict__ pc)
{
    const int b = blockIdx.x, tc = blockIdx.y;
    const int h8 = threadIdx.x;
    const float* al = alpha + (size_t)b * 256 + tc * 64;
    float acc[8];
#pragma unroll
    for (int j = 0; j < 8; ++j) acc[j] = 0.f;
#pragma unroll 4
    for (int i = 0; i < 64; ++i) {
        float a = al[i];
        u16x8 e = *(const u16x8*)(encB + ((size_t)(tc * 64 + i) * 256 + b) * 1024 + h8 * 8);
#pragma unroll
        for (int j = 0; j < 8; ++j) acc[j] += bf2f(e[j]) * a;
    }
    float* d = pc + ((size_t)tc * 256 + b) * 1024 + h8 * 8;
    *(f32x4*)d = *(f32x4*)&acc[0];
    *(f32x4*)(d + 4) = *(f32x4*)&acc[4];
}

// fallback f32 ctx_part
__global__ __launch_bounds__(256) void ctx_part(const float* __restrict__ alpha,
                                                const float* __restrict__ enc,
                                                float* __restrict__ pc)
{
    const int b = blockIdx.x, tc = blockIdx.y;
    const int h4 = threadIdx.x;
    const float* al = alpha + (size_t)b * 256 + tc * 64;
    f32x4 acc = {0.f, 0.f, 0.f, 0.f};
#pragma unroll 4
    for (int i = 0; i < 64; ++i) {
        float a = al[i];
        f32x4 e = *(const f32x4*)(enc + ((size_t)(tc * 64 + i) * 256 + b) * 1024 + h4 * 4);
        acc += e * a;
    }
    *(f32x4*)(pc + ((size_t)tc * 256 + b) * 1024 + h4 * 4) = acc;
}

// reduce context partials -> x_bf16[:,0:1024]
__global__ void ctx_fin(const float* __restrict__ pc, unsigned short* __restrict__ xB)
{
    const int b = blockIdx.x, h4 = threadIdx.x;
    f32x4 c = {0.f, 0.f, 0.f, 0.f};
#pragma unroll
    for (int tc = 0; tc < 4; ++tc)
        c += *(const f32x4*)(pc + ((size_t)tc * 256 + b) * 1024 + h4 * 4);
    u16x4 o;
#pragma unroll
    for (int j = 0; j < 4; ++j) o[j] = f2bf(c[j]);
    *(u16x4*)(xB + (size_t)b * 2048 + h4 * 4) = o;
}

// GRU elementwise (PyTorch gate order r,z,n)
__global__ void gru_kernel(const float* __restrict__ gi, const float* __restrict__ gh,
                           const float* __restrict__ h0, float* __restrict__ hnew,
                           unsigned short* __restrict__ hnB)
{
    int idx = blockIdx.x * 256 + threadIdx.x;
    int b = idx >> 10, h = idx & 1023;
    size_t gb = (size_t)b * 3072;
    float r = fast_sigmoid(gi[gb + h]        + gh[gb + h]);
    float z = fast_sigmoid(gi[gb + 1024 + h] + gh[gb + 1024 + h]);
    float n = fast_tanh   (gi[gb + 2048 + h] + r * gh[gb + 2048 + h]);
    float hp = h0[idx];
    float hn = (1.f - z) * n + z * hp;
    hnew[idx] = hn;
    hnB[idx] = f2bf(hn);
}

// merge per-row (max,sumexp) partials -> lse[m]
__global__ void lse_reduce(const float* __restrict__ lsepart, float* __restrict__ lse, int nbn)
{
    const int m = blockIdx.x, l = threadIdx.x;
    float mx = -3.4e38f, s = 0.f;
    for (int p = l; p < nbn; p += 64) {
        float pm = lsepart[((size_t)m * nbn + p) * 2];
        float ps = lsepart[((size_t)m * nbn + p) * 2 + 1];
        float nm = fmaxf(mx, pm);
        s = s * __expf(mx - nm) + ps * __expf(pm - nm);
        mx = nm;
    }
#pragma unroll
    for (int d = 1; d < 64; d <<= 1) {
        float om = __shfl_xor(mx, d), os = __shfl_xor(s, d);
        float nm = fmaxf(mx, om);
        s = s * __expf(mx - nm) + os * __expf(om - nm);
        mx = nm;
    }
    if (l == 0) lse[m] = mx + __logf(s);
}

// out[m,v] = bf2f(lgB[m,v]) - lse[m]   (8 elems/thread)
__global__ void lsub_bf(const unsigned short* __restrict__ lgB,
                        const float* __restrict__ lse, float* __restrict__ out)
{
    int f = blockIdx.x * 256 + threadIdx.x;
    float l = lse[f / 4000];
    u16x8 v = *(const u16x8*)(lgB + (size_t)f * 8);
    float* o = out + (size_t)f * 8;
    f32x4 o0, o1;
#pragma unroll
    for (int j = 0; j < 4; ++j) o0[j] = bf2f(v[j]) - l;
#pragma unroll
    for (int j = 0; j < 4; ++j) o1[j] = bf2f(v[4 + j]) - l;
    *(f32x4*)o = o0;
    *(f32x4*)(o + 4) = o1;
}

// ---------------------------------------------------------------------------
extern "C" void kernel_launch(void* const* d_in, const int* in_sizes, int n_in,
                              void* d_out, int out_size, void* d_ws, size_t ws_size,
                              hipStream_t stream)
{
    const int*   tokens  = (const int*)  d_in[0];
    const float* h0      = (const float*)d_in[1];
    const float* enc     = (const float*)d_in[2];
    const float* emb     = (const float*)d_in[3];
    const float* W_i2h   = (const float*)d_in[4];
    const float* W_h2h   = (const float*)d_in[5];
    const float* b_h2h   = (const float*)d_in[6];
    const float* w_score = (const float*)d_in[7];
    const float* W_ih    = (const float*)d_in[8];
    const float* b_ih    = (const float*)d_in[9];
    const float* W_hh    = (const float*)d_in[10];
    const float* b_hh    = (const float*)d_in[11];
    const float* W_out   = (const float*)d_in[12];
    const float* b_out   = (const float*)d_in[13];

    float* out   = (float*)d_out;
    float* hnew  = out + (size_t)256 * 32000;
    float* alpha = hnew + 256 * 1024;

    const size_t RS_LDS = 2u * 2u * 128u * LDS_STRIDE * 2u;  // 73728 B

    char* w = (char*)d_ws;
    const size_t NEED = (size_t)153 * (1 << 20);

    if (ws_size >= NEED) {
        unsigned short* encB  = (unsigned short*)(w);                           // 128 MB
        unsigned short* lgB   = (unsigned short*)(w);                           // 16.4 MB, reuses dead encB
        unsigned short* WiB   = (unsigned short*)(w + (size_t)128 * (1 << 20)); // 2 MB
        float* hproj          = (float*)(w + (size_t)130 * (1 << 20));          // 1 MB
        float* gh             = (float*)(w + (size_t)131 * (1 << 20));          // 3 MB
        float* epart          = (float*)(w + (size_t)134 * (1 << 20));          // 4 MB [b][t][16]
        float* pc             = (float*)(w + (size_t)138 * (1 << 20));          // 4 MB
        unsigned short* xB    = (unsigned short*)(w + (size_t)142 * (1 << 20)); // 1 MB
        float* gi             = (float*)(w + (size_t)143 * (1 << 20));          // 3 MB
        unsigned short* hnB   = (unsigned short*)(w + (size_t)146 * (1 << 20)); // 0.5 MB
        float* lsepart        = (float*)(w + (size_t)147 * (1 << 20));          // 0.5 MB
        float* lse            = (float*)(w + (size_t)148 * (1 << 20));          // 1 KB

        prep_all<<<2048, 256, 0, stream>>>(enc, encB, W_i2h, WiB, emb, tokens, xB);
        gemm_h2<<<64, 256, RS_LDS, stream>>>(h0, W_h2h, W_hh, b_h2h, b_hh, hproj, gh);
        gemm_bg<<<4096, 256, 0, stream>>>(encB, WiB, hproj, w_score, epart);
        softmax_alpha<<<256, 256, 0, stream>>>(epart, alpha, 16);
        ctx_part_bf<<<dim3(256, 4), 128, 0, stream>>>(alpha, encB, pc);
        ctx_fin<<<256, 256, 0, stream>>>(pc, xB);
        gemm_rs<0, true, false><<<48, 256, RS_LDS, stream>>>(xB, W_ih, b_ih, gi,
            nullptr, nullptr, nullptr, nullptr, nullptr, 256, 3072, 2048);
        gru_kernel<<<1024, 256, 0, stream>>>(gi, gh, h0, hnew, hnB);
        // encB is dead past this point; lgB overlays it
        gemm_rs<2, true, false><<<500, 256, RS_LDS, stream>>>(hnB, W_out, b_out, nullptr,
            lgB, nullptr, nullptr, nullptr, lsepart, 256, 32000, 1024);
        lse_reduce<<<256, 64, 0, stream>>>(lsepart, lse, 250);
        lsub_bf<<<4000, 256, 0, stream>>>(lgB, lse, out);
    } else {
        // fallback: reg-staged everywhere (ws >= 36 MB)
        unsigned short* WiB   = (unsigned short*)(w);
        float* hproj          = (float*)(w + (size_t)2  * (1 << 20));
        float* gh             = (float*)(w + (size_t)3  * (1 << 20));
        float* epart          = (float*)(w + (size_t)6  * (1 << 20));
        float* pc             = (float*)(w + (size_t)8  * (1 << 20));
        unsigned short* xB    = (unsigned short*)(w + (size_t)12 * (1 << 20));
        float* gi             = (float*)(w + (size_t)13 * (1 << 20));
        unsigned short* hnB   = (unsigned short*)(w + (size_t)16 * (1 << 20));
        float* lsepart        = (float*)(w + (size_t)17 * (1 << 20));
        float* lse            = (float*)(w + (size_t)18 * (1 << 20));
        unsigned short* lgB   = (unsigned short*)(w + (size_t)19 * (1 << 20));

        prep_kernel<<<1280, 256, 0, stream>>>(W_i2h, WiB, emb, tokens, xB);
        gemm_h2<<<64, 256, RS_LDS, stream>>>(h0, W_h2h, W_hh, b_h2h, b_hh, hproj, gh);
        gemm_rs<1, false, true><<<4096, 256, RS_LDS, stream>>>(enc, WiB, nullptr, nullptr,
            nullptr, hproj, w_score, epart, nullptr, 65536, 1024, 1024);
        softmax_alpha<<<256, 256, 0, stream>>>(epart, alpha, 8);
        ctx_part<<<dim3(256, 4), 256, 0, stream>>>(alpha, enc, pc);
        ctx_fin<<<256, 256, 0, stream>>>(pc, xB);
        gemm_rs<0, true, false><<<48, 256, RS_LDS, stream>>>(xB, W_ih, b_ih, gi,
            nullptr, nullptr, nullptr, nullptr, nullptr, 256, 3072, 2048);
        gru_kernel<<<1024, 256, 0, stream>>>(gi, gh, h0, hnew, hnB);
        gemm_rs<2, true, false><<<500, 256, RS_LDS, stream>>>(hnB, W_out, b_out, nullptr,
            lgB, nullptr, nullptr, nullptr, lsepart, 256, 32000, 1024);
        lse_reduce<<<256, 64, 0, stream>>>(lsepart, lse, 250);
        lsub_bf<<<4000, 256, 0, stream>>>(lgB, lse, out);
    }
}

// Round 9
// 479.280 us; speedup vs baseline: 1.2492x; 1.2492x over previous
//
#include <hip/hip_runtime.h>
#include <hip/hip_bf16.h>

typedef __attribute__((ext_vector_type(8))) short bf16x8;
typedef __attribute__((ext_vector_type(4))) float f32x4;
typedef __attribute__((ext_vector_type(4))) int i32x4;
typedef __attribute__((ext_vector_type(4))) unsigned short u16x4;
typedef __attribute__((ext_vector_type(8))) unsigned short u16x8;

#define LDS_STRIDE 72   // reg-staged kernel only

__device__ __forceinline__ unsigned short f2bf(float f) {
    __hip_bfloat16 h = __float2bfloat16(f);
    unsigned short u; __builtin_memcpy(&u, &h, 2); return u;
}
__device__ __forceinline__ float bf2f(unsigned short u) {
    union { unsigned u; float f; } v; v.u = ((unsigned)u) << 16; return v.f;
}
__device__ __forceinline__ float fast_sigmoid(float x) { return 1.f / (1.f + __expf(-x)); }
__device__ __forceinline__ float fast_tanh(float x)    { return 1.f - 2.f / (__expf(2.f * x) + 1.f); }

#define GLOAD_LDS16(gp, lp) __builtin_amdgcn_global_load_lds( \
    (const __attribute__((address_space(1))) void*)(gp), \
    (__attribute__((address_space(3))) void*)(lp), 16, 0, 0)

// ===========================================================================
// 8-phase 256x256 e-GEMM, r9: r7 base (one barrier/phase, pre-issued ds_reads)
// + 3-deep A prefetch. Mechanism: A comes from HBM (~900cy); r7's A gap was
// ~3 phases (~500-750cy) -> stall at every vmcnt. Now A(t+2)@p1/2, A(t+3)@p5/6
// -> 8-phase gap (~2000cy). B (L2-hot, ~200cy) keeps 2-buf / 2-ahead.
// vmcnt(8) everywhere (8 newest = current iter's stages may fly; the tile
// about to be read is older -> landed). Tail t=14 p4: vmcnt(0) (nothing newer
// outstanding; r5's latent-race case handled explicitly).
// LDS = A[3] 96KB + B[2] 64KB = 160KB (1 block/CU, as r7).
// WAR ledger (1 barrier/phase): A buf (t+2)%3 last read by tile t-1 (prev
// iter p5-p8, last pre-issue p7, consumed p8) -> STA at p1 is 1+ barrier
// later. A buf t%3 (for A(t+3) at p5) last read p4-window -> p4-end barrier.
// B buf0 reads complete in p1-window (bvA+bvB both pre-loaded) -> STB p3/p4;
// B buf1 reads complete p5 -> STB p7/p8.
// ===========================================================================

#define STA(LB, HF, PTR) do { \
    GLOAD_LDS16((PTR), &AL[LB][HF][ldsrow][0]); \
    GLOAD_LDS16((PTR) + 65536, &AL[LB][HF][64 + ldsrow][0]); \
} while (0)

#define STB(LB, HF, PTR) do { \
    GLOAD_LDS16((PTR), &BL[LB][HF][ldsrow][0]); \
    GLOAD_LDS16((PTR) + 65536, &BL[LB][HF][64 + ldsrow][0]); \
} while (0)

#define LDA(DST, BUF, MH, KS) do { \
    const int c_ = ((KS)*32 + fg*8) ^ swzr; \
    _Pragma("unroll") \
    for (int mi = 0; mi < 4; ++mi) \
        DST[mi] = *(const bf16x8*)&AL[BUF][wr][(MH)*64 + mi*16 + fr][c_]; \
} while (0)

#define LDB(DST, BUF, KS) do { \
    const int c_ = ((KS)*32 + fg*8) ^ swzr; \
    _Pragma("unroll") \
    for (int ni = 0; ni < 4; ++ni) \
        DST[ni] = *(const bf16x8*)&BL[BUF][bh][br0 + ni*16 + fr][c_]; \
} while (0)

#define MM(AV, BV, MH) do { \
    _Pragma("unroll") \
    for (int mi = 0; mi < 4; ++mi) \
        _Pragma("unroll") \
        for (int ni = 0; ni < 4; ++ni) \
            acc[(MH)*4 + mi][ni] = __builtin_amdgcn_mfma_f32_16x16x32_bf16( \
                AV[mi], BV[ni], acc[(MH)*4 + mi][ni], 0, 0, 0); \
} while (0)

#define SP1 __builtin_amdgcn_s_setprio(1)
#define SP0 __builtin_amdgcn_s_setprio(0)
#define BAR asm volatile("s_barrier" ::: "memory")
#define VMC8 asm volatile("s_waitcnt vmcnt(8)" ::: "memory")
#define VMC0 asm volatile("s_waitcnt vmcnt(0)" ::: "memory")

__global__ __launch_bounds__(512, 1)
void gemm8p_e(const unsigned short* __restrict__ Ag, const unsigned short* __restrict__ Bg,
              const float* __restrict__ hproj, const float* __restrict__ wscore,
              float* __restrict__ epart)
{
    const int tid = threadIdx.x;
    const int lane = tid & 63, wid = tid >> 6;
    const int fr = lane & 15, fg = lane >> 4;
    const int wr = wid >> 2;                 // M half (0..1)
    const int wc = wid & 3;                  // N quarter (0..3)
    const int bh = wc >> 1, br0 = (wc & 1) * 64;

    // bijective XCD-contiguous remap (gridDim.x = 1024, %8 == 0)
    const int cpx = (int)gridDim.x >> 3;
    const int swz = ((int)blockIdx.x & 7) * cpx + ((int)blockIdx.x >> 3);
    const int mb = swz >> 2, nb = swz & 3;   // nb-minor: A-tile shared within XCD
    const int m0 = mb << 8, n0 = nb << 8;

    __shared__ unsigned short AL[3][2][128][64];   // 96 KB: 3-deep A
    __shared__ unsigned short BL[2][2][128][64];   // 64 KB: 2-deep B

    const int srow = lane >> 3;
    const int scol = ((lane & 7) ^ srow) << 3;     // inverse-swizzled global col
    const int swzr = (fr & 7) << 3;                // ds_read swizzle
    const int ldsrow = wid * 8;                    // wave-uniform LDS dest row

    const unsigned short* pA0 = Ag + (size_t)(m0 + ldsrow + srow) * 1024 + scol;
    const unsigned short* pA1 = pA0 + (size_t)128 * 1024;
    const unsigned short* pB0 = Bg + (size_t)(n0 + ldsrow + srow) * 1024 + scol;
    const unsigned short* pB1 = pB0 + (size_t)128 * 1024;

    f32x4 acc[8][4];
#pragma unroll
    for (int i = 0; i < 8; ++i)
#pragma unroll
        for (int j = 0; j < 4; ++j) acc[i][j] = (f32x4){0.f, 0.f, 0.f, 0.f};
    bf16x8 avA[4], avB[4], bvA[4], bvB[4];

    // prologue: A0,B0,A1,B1 (16 loads); vmcnt(8) -> tile0 (8 oldest) landed
    STA(0, 0, pA0);      STA(0, 1, pA1);
    STB(0, 0, pB0);      STB(0, 1, pB1);
    STA(1, 0, pA0 + 64); STA(1, 1, pA1 + 64);
    STB(1, 0, pB0 + 64); STB(1, 1, pB1 + 64);
    VMC8;
    BAR;

#pragma unroll
    for (int t = 0; t < 16; t += 2) {
        const int tof = t * 64;
        const int a0 = t % 3, a1 = (t + 1) % 3, a2 = (t + 2) % 3, a3 = (t + 3) % 3;
        // ---- tile t (A buf a0, B buf 0) ----
        // p1: top-load; MFMA mh0/ks0; pre p2; stage A(t+2)lo -> buf a2
        LDB(bvA, 0, 0); LDA(avA, a0, 0, 0);
        SP1; MM(avA, bvA, 0); SP0;
        LDB(bvB, 0, 1); LDA(avB, a0, 0, 1);
        if (t + 2 < 16) STA(a2, 0, pA0 + tof + 128);
        BAR;
        // p2: MFMA mh0/ks1; pre p3; stage A(t+2)hi
        SP1; MM(avB, bvB, 0); SP0;
        LDA(avA, a0, 1, 0);
        if (t + 2 < 16) STA(a2, 1, pA1 + tof + 128);
        BAR;
        // p3: MFMA mh1/ks0; pre p4; stage B(t+2)lo (buf0B reads ended p1)
        SP1; MM(avA, bvA, 1); SP0;
        LDA(avB, a0, 1, 1);
        if (t + 2 < 16) STB(0, 0, pB0 + tof + 128);
        BAR;
        // p4: MFMA mh1/ks1; stage B(t+2)hi; vmcnt(8) -> A(t+1),B(t+1) landed
        SP1; MM(avB, bvB, 1); SP0;
        if (t + 2 < 16) { STB(0, 1, pB1 + tof + 128); VMC8; } else { VMC0; }
        BAR;
        // ---- tile t+1 (A buf a1, B buf 1) ----
        // p5: top-load; stage A(t+3)lo -> buf a3 (= buf a0, reads ended p4)
        LDB(bvA, 1, 0); LDA(avA, a1, 0, 0);
        SP1; MM(avA, bvA, 0); SP0;
        LDB(bvB, 1, 1); LDA(avB, a1, 0, 1);
        if (t + 3 < 16) STA(a3, 0, pA0 + tof + 192);
        BAR;
        // p6
        SP1; MM(avB, bvB, 0); SP0;
        LDA(avA, a1, 1, 0);
        if (t + 3 < 16) STA(a3, 1, pA1 + tof + 192);
        BAR;
        // p7
        SP1; MM(avA, bvA, 1); SP0;
        LDA(avB, a1, 1, 1);
        if (t + 3 < 16) STB(1, 0, pB0 + tof + 192);
        BAR;
        // p8: vmcnt(8) -> A(t+2),B(t+2) (8-oldest) landed for next p1
        SP1; MM(avB, bvB, 1); SP0;
        if (t + 3 < 16) { STB(1, 1, pB1 + tof + 192); VMC8; }
        BAR;
    }

    // ---- epilogue: fused tanh-dot-wscore row partials ----
    float wsv[4];
#pragma unroll
    for (int ni = 0; ni < 4; ++ni) wsv[ni] = wscore[n0 + wc * 64 + ni * 16 + fr];
#pragma unroll
    for (int mi = 0; mi < 8; ++mi)
#pragma unroll
        for (int r = 0; r < 4; ++r) {
            const int bb = wr * 128 + mi * 16 + fg * 4 + r;   // batch; tt = mb
            const float* hp = hproj + (size_t)bb * 1024 + n0 + wc * 64 + fr;
            float s = 0.f;
#pragma unroll
            for (int ni = 0; ni < 4; ++ni)
                s += fast_tanh(acc[mi][ni][r] + hp[ni * 16]) * wsv[ni];
            s += __shfl_xor(s, 1); s += __shfl_xor(s, 2);
            s += __shfl_xor(s, 4); s += __shfl_xor(s, 8);
            if (fr == 0) epart[((size_t)bb * 256 + mb) * 16 + nb * 4 + wc] = s;
        }
}

// ---------------------------------------------------------------------------
// Fused h-projection GEMM (r8-verified): hproj + gh in one launch.
// ---------------------------------------------------------------------------
__global__ __launch_bounds__(256, 2)
void gemm_h2(const float* __restrict__ h0,
             const float* __restrict__ Wh2h, const float* __restrict__ Whh,
             const float* __restrict__ bh2h, const float* __restrict__ bhh,
             float* __restrict__ hproj, float* __restrict__ gh)
{
    const int mb = blockIdx.x & 1;
    const int nbg = blockIdx.x >> 1;
    const float* Bf; const float* bias; float* Cout; int Nst; int n0;
    if (nbg < 8) { Bf = Wh2h; bias = bh2h; Cout = hproj; Nst = 1024; n0 = nbg << 7; }
    else         { Bf = Whh;  bias = bhh;  Cout = gh;    Nst = 3072; n0 = (nbg - 8) << 7; }

    const int m0 = mb << 7;
    const int tid = threadIdx.x;
    const int lane = tid & 63, wid = tid >> 6;
    const int fr = lane & 15, fg = lane >> 4;
    const int srow = tid >> 1, shalf = (tid & 1) * 32;

    extern __shared__ char smem[];
    typedef unsigned short (*tile_t)[128][LDS_STRIDE];
    tile_t As = (tile_t)smem;
    tile_t Bs = (tile_t)(smem + 2 * 128 * LDS_STRIDE * 2);

    f32x4 acc[2][8];
#pragma unroll
    for (int i = 0; i < 2; ++i)
#pragma unroll
        for (int j = 0; j < 8; ++j) acc[i][j] = (f32x4){0.f, 0.f, 0.f, 0.f};

    float a_f[32], b_f[32];

    auto loadA = [&](int kt) {
        size_t base = (size_t)(m0 + srow) * 1024 + (size_t)kt * 64 + shalf;
#pragma unroll
        for (int j = 0; j < 8; ++j) *(f32x4*)&a_f[j * 4] = *(const f32x4*)(h0 + base + j * 4);
    };
    auto loadB = [&](int kt) {
        size_t base = (size_t)(n0 + srow) * 1024 + (size_t)kt * 64 + shalf;
#pragma unroll
        for (int j = 0; j < 8; ++j) *(f32x4*)&b_f[j * 4] = *(const f32x4*)(Bf + base + j * 4);
    };
    auto storeA = [&](int buf) {
        unsigned short t[32];
#pragma unroll
        for (int j = 0; j < 32; ++j) t[j] = f2bf(a_f[j]);
#pragma unroll
        for (int j = 0; j < 4; ++j) *(i32x4*)&As[buf][srow][shalf + j * 8] = *(i32x4*)&t[j * 8];
    };
    auto storeB = [&](int buf) {
        unsigned short t[32];
#pragma unroll
        for (int j = 0; j < 32; ++j) t[j] = f2bf(b_f[j]);
#pragma unroll
        for (int j = 0; j < 4; ++j) *(i32x4*)&Bs[buf][srow][shalf + j * 8] = *(i32x4*)&t[j * 8];
    };

    loadA(0); loadB(0);
    storeA(0); storeB(0);
    __syncthreads();

    for (int kt = 0; kt < 16; ++kt) {
        const int cur = kt & 1;
        if (kt + 1 < 16) { loadA(kt + 1); loadB(kt + 1); }
#pragma unroll
        for (int ks = 0; ks < 2; ++ks) {
            bf16x8 av[2], bv[8];
#pragma unroll
            for (int mi = 0; mi < 2; ++mi)
                av[mi] = *(const bf16x8*)&As[cur][wid * 32 + mi * 16 + fr][ks * 32 + fg * 8];
#pragma unroll
            for (int ni = 0; ni < 8; ++ni)
                bv[ni] = *(const bf16x8*)&Bs[cur][ni * 16 + fr][ks * 32 + fg * 8];
#pragma unroll
            for (int mi = 0; mi < 2; ++mi)
#pragma unroll
                for (int ni = 0; ni < 8; ++ni)
                    acc[mi][ni] = __builtin_amdgcn_mfma_f32_16x16x32_bf16(av[mi], bv[ni], acc[mi][ni], 0, 0, 0);
        }
        if (kt + 1 < 16) { storeA(cur ^ 1); storeB(cur ^ 1); }
        __syncthreads();
    }

#pragma unroll
    for (int mi = 0; mi < 2; ++mi)
#pragma unroll
        for (int r = 0; r < 4; ++r) {
            const int m = m0 + wid * 32 + mi * 16 + fg * 4 + r;
#pragma unroll
            for (int ni = 0; ni < 8; ++ni) {
                const int col = n0 + ni * 16 + fr;
                Cout[(size_t)m * Nst + col] = acc[mi][ni][r] + bias[col];
            }
        }
}

// ---------------------------------------------------------------------------
// Reg-staged GEMM — gi GEMM (EPI0), fallback e-GEMM (EPI1), logits (EPI2).
// ---------------------------------------------------------------------------
template<int EPI, bool ABF, bool BBF>
__global__ __launch_bounds__(256, 2)
void gemm_rs(const void* __restrict__ Agv, const void* __restrict__ Bgv,
             const float* __restrict__ bias, float* __restrict__ Cout,
             unsigned short* __restrict__ CoutB,
             const float* __restrict__ hproj, const float* __restrict__ wscore,
             float* __restrict__ epart, float* __restrict__ lsepart,
             int M, int N, int K)
{
    const int nbn = N >> 7;
    const int nmb = M >> 7;
    int mb, nb;
    if (EPI == 1) {
        int cpx = gridDim.x >> 3;
        int bp = (blockIdx.x & 7) * cpx + (blockIdx.x >> 3);
        mb = bp / nbn; nb = bp % nbn;
    } else {
        mb = blockIdx.x % nmb; nb = blockIdx.x / nmb;
    }
    const int m0 = mb << 7, n0 = nb << 7;
    const int tid = threadIdx.x;
    const int lane = tid & 63, wid = tid >> 6;
    const int fr = lane & 15, fg = lane >> 4;
    const int srow = tid >> 1, shalf = (tid & 1) * 32;

    extern __shared__ char smem[];
    typedef unsigned short (*tile_t)[128][LDS_STRIDE];
    tile_t As = (tile_t)smem;
    tile_t Bs = (tile_t)(smem + 2 * 128 * LDS_STRIDE * 2);

    const float* Af = (const float*)Agv;
    const unsigned short* Ab = (const unsigned short*)Agv;
    const float* Bf = (const float*)Bgv;
    const unsigned short* Bb = (const unsigned short*)Bgv;

    f32x4 acc[2][8];
#pragma unroll
    for (int i = 0; i < 2; ++i)
#pragma unroll
        for (int j = 0; j < 8; ++j) acc[i][j] = (f32x4){0.f, 0.f, 0.f, 0.f};

    float a_f[32]; unsigned short a_b[32];
    float b_f[32]; unsigned short b_b[32];

    auto loadA = [&](int kt) {
        size_t base = (size_t)(m0 + srow) * K + (size_t)kt * 64 + shalf;
        if (ABF) {
#pragma unroll
            for (int j = 0; j < 4; ++j) *(i32x4*)&a_b[j * 8] = *(const i32x4*)(Ab + base + j * 8);
        } else {
#pragma unroll
            for (int j = 0; j < 8; ++j) *(f32x4*)&a_f[j * 4] = *(const f32x4*)(Af + base + j * 4);
        }
    };
    auto loadB = [&](int kt) {
        size_t base = (size_t)(n0 + srow) * K + (size_t)kt * 64 + shalf;
        if (BBF) {
#pragma unroll
            for (int j = 0; j < 4; ++j) *(i32x4*)&b_b[j * 8] = *(const i32x4*)(Bb + base + j * 8);
        } else {
#pragma unroll
            for (int j = 0; j < 8; ++j) *(f32x4*)&b_f[j * 4] = *(const f32x4*)(Bf + base + j * 4);
        }
    };
    auto storeA = [&](int buf) {
        unsigned short tA[32];
        if (ABF) {
#pragma unroll
            for (int j = 0; j < 32; ++j) tA[j] = a_b[j];
        } else {
#pragma unroll
            for (int j = 0; j < 32; ++j) tA[j] = f2bf(a_f[j]);
        }
#pragma unroll
        for (int j = 0; j < 4; ++j) *(i32x4*)&As[buf][srow][shalf + j * 8] = *(i32x4*)&tA[j * 8];
    };
    auto storeB = [&](int buf) {
        unsigned short tB[32];
        if (BBF) {
#pragma unroll
            for (int j = 0; j < 32; ++j) tB[j] = b_b[j];
        } else {
#pragma unroll
            for (int j = 0; j < 32; ++j) tB[j] = f2bf(b_f[j]);
        }
#pragma unroll
        for (int j = 0; j < 4; ++j) *(i32x4*)&Bs[buf][srow][shalf + j * 8] = *(i32x4*)&tB[j * 8];
    };

    const int nkt = K >> 6;

    loadA(0); loadB(0);
    storeA(0); storeB(0);
    __syncthreads();

    for (int kt = 0; kt < nkt; ++kt) {
        const int cur = kt & 1;
        if (kt + 1 < nkt) { loadA(kt + 1); loadB(kt + 1); }
#pragma unroll
        for (int ks = 0; ks < 2; ++ks) {
            bf16x8 av[2], bv[8];
#pragma unroll
            for (int mi = 0; mi < 2; ++mi)
                av[mi] = *(const bf16x8*)&As[cur][wid * 32 + mi * 16 + fr][ks * 32 + fg * 8];
#pragma unroll
            for (int ni = 0; ni < 8; ++ni)
                bv[ni] = *(const bf16x8*)&Bs[cur][ni * 16 + fr][ks * 32 + fg * 8];
#pragma unroll
            for (int mi = 0; mi < 2; ++mi)
#pragma unroll
                for (int ni = 0; ni < 8; ++ni)
                    acc[mi][ni] = __builtin_amdgcn_mfma_f32_16x16x32_bf16(av[mi], bv[ni], acc[mi][ni], 0, 0, 0);
        }
        if (kt + 1 < nkt) { storeA(cur ^ 1); storeB(cur ^ 1); }
        __syncthreads();
    }

    if (EPI == 0) {
#pragma unroll
        for (int mi = 0; mi < 2; ++mi)
#pragma unroll
            for (int r = 0; r < 4; ++r) {
                const int m = m0 + wid * 32 + mi * 16 + fg * 4 + r;
#pragma unroll
                for (int ni = 0; ni < 8; ++ni) {
                    const int col = n0 + ni * 16 + fr;
                    Cout[(size_t)m * N + col] = acc[mi][ni][r] + bias[col];
                }
            }
    } else if (EPI == 1) {
        float wsv[8];
#pragma unroll
        for (int ni = 0; ni < 8; ++ni) wsv[ni] = wscore[n0 + ni * 16 + fr];
#pragma unroll
        for (int mi = 0; mi < 2; ++mi)
#pragma unroll
            for (int r = 0; r < 4; ++r) {
                const int m = m0 + wid * 32 + mi * 16 + fg * 4 + r;
                const int bb = m & 255, tt = m >> 8;
                const float* hp = hproj + (size_t)bb * 1024 + n0 + fr;
                float s = 0.f;
#pragma unroll
                for (int ni = 0; ni < 8; ++ni)
                    s += fast_tanh(acc[mi][ni][r] + hp[ni * 16]) * wsv[ni];
                s += __shfl_xor(s, 1); s += __shfl_xor(s, 2);
                s += __shfl_xor(s, 4); s += __shfl_xor(s, 8);
                if (fr == 0) epart[((size_t)bb * 256 + tt) * 8 + nb] = s;
            }
    } else {  // EPI 2: bf16 logits + (max,sumexp) partials
#pragma unroll
        for (int mi = 0; mi < 2; ++mi)
#pragma unroll
            for (int r = 0; r < 4; ++r) {
                const int m = m0 + wid * 32 + mi * 16 + fg * 4 + r;
                float vv[8];
                float mx = -3.4e38f;
#pragma unroll
                for (int ni = 0; ni < 8; ++ni) {
                    const int col = n0 + ni * 16 + fr;
                    vv[ni] = acc[mi][ni][r] + bias[col];
                    CoutB[(size_t)m * N + col] = f2bf(vv[ni]);
                    mx = fmaxf(mx, vv[ni]);
                }
                mx = fmaxf(mx, __shfl_xor(mx, 1));
                mx = fmaxf(mx, __shfl_xor(mx, 2));
                mx = fmaxf(mx, __shfl_xor(mx, 4));
                mx = fmaxf(mx, __shfl_xor(mx, 8));
                float se = 0.f;
#pragma unroll
                for (int ni = 0; ni < 8; ++ni) se += __expf(vv[ni] - mx);
                se += __shfl_xor(se, 1); se += __shfl_xor(se, 2);
                se += __shfl_xor(se, 4); se += __shfl_xor(se, 8);
                if (fr == 0) {
                    lsepart[((size_t)m * nbn + nb) * 2]     = mx;
                    lsepart[((size_t)m * nbn + nb) * 2 + 1] = se;
                }
            }
    }
}

// ---------------------------------------------------------------------------
// merged prep: enc f32->bf16 + W_i2h f32->bf16 + emb gather (grid-stride)
__global__ void prep_all(const float* __restrict__ enc, unsigned short* __restrict__ encB,
                         const float* __restrict__ Wi2h, unsigned short* __restrict__ WiB,
                         const float* __restrict__ emb, const int* __restrict__ tokens,
                         unsigned short* __restrict__ xB)
{
    const int ENC4 = 16777216, WI4 = 262144, EMB4 = 65536;
    const int total = ENC4 + WI4 + EMB4;
    for (int i = blockIdx.x * 256 + threadIdx.x; i < total; i += gridDim.x * 256) {
        f32x4 v; unsigned short* dst;
        if (i < ENC4) {
            v = *(const f32x4*)(enc + (size_t)i * 4);
            dst = encB + (size_t)i * 4;
        } else if (i < ENC4 + WI4) {
            int j = i - ENC4;
            v = *(const f32x4*)(Wi2h + (size_t)j * 4);
            dst = WiB + (size_t)j * 4;
        } else {
            int j = i - ENC4 - WI4;
            int b = j >> 8, h4 = j & 255;
            v = *(const f32x4*)(emb + (size_t)tokens[b] * 1024 + h4 * 4);
            dst = xB + (size_t)b * 2048 + 1024 + h4 * 4;
        }
        u16x4 o;
#pragma unroll
        for (int j = 0; j < 4; ++j) o[j] = f2bf(v[j]);
        *(u16x4*)dst = o;
    }
}

// fallback prep: W_i2h conv + emb gather only
__global__ void prep_kernel(const float* __restrict__ Wi2h, unsigned short* __restrict__ WiB,
                            const float* __restrict__ emb, const int* __restrict__ tokens,
                            unsigned short* __restrict__ xB)
{
    int i = blockIdx.x * 256 + threadIdx.x;
    if (i < 262144) {
        f32x4 v = *(const f32x4*)(Wi2h + (size_t)i * 4);
        u16x4 o;
#pragma unroll
        for (int j = 0; j < 4; ++j) o[j] = f2bf(v[j]);
        *(u16x4*)(WiB + (size_t)i * 4) = o;
    } else {
        int j = i - 262144;
        int b = j >> 8, h4 = j & 255;
        int tok = tokens[b];
        f32x4 v = *(const f32x4*)(emb + (size_t)tok * 1024 + h4 * 4);
        u16x4 o;
#pragma unroll
        for (int jj = 0; jj < 4; ++jj) o[jj] = f2bf(v[jj]);
        *(u16x4*)(xB + (size_t)b * 2048 + 1024 + h4 * 4) = o;
    }
}

// softmax over t per batch b; epart is [b][t][pw] partials
__global__ __launch_bounds__(256) void softmax_alpha(const float* __restrict__ epart,
                                                     float* __restrict__ alpha, int pw)
{
    const int b = blockIdx.x, t = threadIdx.x;
    const int lane = t & 63, w = t >> 6;
    const float* ep = epart + ((size_t)b * 256 + t) * pw;
    float s = 0.f;
    for (int j = 0; j < pw; ++j) s += ep[j];
    __shared__ float rmax[4], rsum[4];
    float mx = s;
#pragma unroll
    for (int d = 1; d < 64; d <<= 1) mx = fmaxf(mx, __shfl_xor(mx, d));
    if (lane == 0) rmax[w] = mx;
    __syncthreads();
    mx = fmaxf(fmaxf(rmax[0], rmax[1]), fmaxf(rmax[2], rmax[3]));
    float p = __expf(s - mx);
    float sm = p;
#pragma unroll
    for (int d = 1; d < 64; d <<= 1) sm += __shfl_xor(sm, d);
    if (lane == 0) rsum[w] = sm;
    __syncthreads();
    sm = rsum[0] + rsum[1] + rsum[2] + rsum[3];
    alpha[(size_t)b * 256 + t] = p / sm;
}

// context partials from bf16 enc
__global__ __launch_bounds__(128) void ctx_part_bf(const float* __restrict__ alpha,
                                                   const unsigned short* __restrict__ encB,
                                                   float* __restrict__ pc)
{
    const int b = blockIdx.x, tc = blockIdx.y;
    const int h8 = threadIdx.x;
    const float* al = alpha + (size_t)b * 256 + tc * 64;
    float acc[8];
#pragma unroll
    for (int j = 0; j < 8; ++j) acc[j] = 0.f;
#pragma unroll 4
    for (int i = 0; i < 64; ++i) {
        float a = al[i];
        u16x8 e = *(const u16x8*)(encB + ((size_t)(tc * 64 + i) * 256 + b) * 1024 + h8 * 8);
#pragma unroll
        for (int j = 0; j < 8; ++j) acc[j] += bf2f(e[j]) * a;
    }
    float* d = pc + ((size_t)tc * 256 + b) * 1024 + h8 * 8;
    *(f32x4*)d = *(f32x4*)&acc[0];
    *(f32x4*)(d + 4) = *(f32x4*)&acc[4];
}

// fallback f32 ctx_part
__global__ __launch_bounds__(256) void ctx_part(const float* __restrict__ alpha,
                                                const float* __restrict__ enc,
                                                float* __restrict__ pc)
{
    const int b = blockIdx.x, tc = blockIdx.y;
    const int h4 = threadIdx.x;
    const float* al = alpha + (size_t)b * 256 + tc * 64;
    f32x4 acc = {0.f, 0.f, 0.f, 0.f};
#pragma unroll 4
    for (int i = 0; i < 64; ++i) {
        float a = al[i];
        f32x4 e = *(const f32x4*)(enc + ((size_t)(tc * 64 + i) * 256 + b) * 1024 + h4 * 4);
        acc += e * a;
    }
    *(f32x4*)(pc + ((size_t)tc * 256 + b) * 1024 + h4 * 4) = acc;
}

// reduce context partials -> x_bf16[:,0:1024]
__global__ void ctx_fin(const float* __restrict__ pc, unsigned short* __restrict__ xB)
{
    const int b = blockIdx.x, h4 = threadIdx.x;
    f32x4 c = {0.f, 0.f, 0.f, 0.f};
#pragma unroll
    for (int tc = 0; tc < 4; ++tc)
        c += *(const f32x4*)(pc + ((size_t)tc * 256 + b) * 1024 + h4 * 4);
    u16x4 o;
#pragma unroll
    for (int j = 0; j < 4; ++j) o[j] = f2bf(c[j]);
    *(u16x4*)(xB + (size_t)b * 2048 + h4 * 4) = o;
}

// GRU elementwise (PyTorch gate order r,z,n)
__global__ void gru_kernel(const float* __restrict__ gi, const float* __restrict__ gh,
                           const float* __restrict__ h0, float* __restrict__ hnew,
                           unsigned short* __restrict__ hnB)
{
    int idx = blockIdx.x * 256 + threadIdx.x;
    int b = idx >> 10, h = idx & 1023;
    size_t gb = (size_t)b * 3072;
    float r = fast_sigmoid(gi[gb + h]        + gh[gb + h]);
    float z = fast_sigmoid(gi[gb + 1024 + h] + gh[gb + 1024 + h]);
    float n = fast_tanh   (gi[gb + 2048 + h] + r * gh[gb + 2048 + h]);
    float hp = h0[idx];
    float hn = (1.f - z) * n + z * hp;
    hnew[idx] = hn;
    hnB[idx] = f2bf(hn);
}

// merge per-row (max,sumexp) partials -> lse[m]
__global__ void lse_reduce(const float* __restrict__ lsepart, float* __restrict__ lse, int nbn)
{
    const int m = blockIdx.x, l = threadIdx.x;
    float mx = -3.4e38f, s = 0.f;
    for (int p = l; p < nbn; p += 64) {
        float pm = lsepart[((size_t)m * nbn + p) * 2];
        float ps = lsepart[((size_t)m * nbn + p) * 2 + 1];
        float nm = fmaxf(mx, pm);
        s = s * __expf(mx - nm) + ps * __expf(pm - nm);
        mx = nm;
    }
#pragma unroll
    for (int d = 1; d < 64; d <<= 1) {
        float om = __shfl_xor(mx, d), os = __shfl_xor(s, d);
        float nm = fmaxf(mx, om);
        s = s * __expf(mx - nm) + os * __expf(om - nm);
        mx = nm;
    }
    if (l == 0) lse[m] = mx + __logf(s);
}

// out[m,v] = bf2f(lgB[m,v]) - lse[m]   (8 elems/thread)
__global__ void lsub_bf(const unsigned short* __restrict__ lgB,
                        const float* __restrict__ lse, float* __restrict__ out)
{
    int f = blockIdx.x * 256 + threadIdx.x;
    float l = lse[f / 4000];
    u16x8 v = *(const u16x8*)(lgB + (size_t)f * 8);
    float* o = out + (size_t)f * 8;
    f32x4 o0, o1;
#pragma unroll
    for (int j = 0; j < 4; ++j) o0[j] = bf2f(v[j]) - l;
#pragma unroll
    for (int j = 0; j < 4; ++j) o1[j] = bf2f(v[4 + j]) - l;
    *(f32x4*)o = o0;
    *(f32x4*)(o + 4) = o1;
}

// ---------------------------------------------------------------------------
extern "C" void kernel_launch(void* const* d_in, const int* in_sizes, int n_in,
                              void* d_out, int out_size, void* d_ws, size_t ws_size,
                              hipStream_t stream)
{
    const int*   tokens  = (const int*)  d_in[0];
    const float* h0      = (const float*)d_in[1];
    const float* enc     = (const float*)d_in[2];
    const float* emb     = (const float*)d_in[3];
    const float* W_i2h   = (const float*)d_in[4];
    const float* W_h2h   = (const float*)d_in[5];
    const float* b_h2h   = (const float*)d_in[6];
    const float* w_score = (const float*)d_in[7];
    const float* W_ih    = (const float*)d_in[8];
    const float* b_ih    = (const float*)d_in[9];
    const float* W_hh    = (const float*)d_in[10];
    const float* b_hh    = (const float*)d_in[11];
    const float* W_out   = (const float*)d_in[12];
    const float* b_out   = (const float*)d_in[13];

    float* out   = (float*)d_out;
    float* hnew  = out + (size_t)256 * 32000;
    float* alpha = hnew + 256 * 1024;

    const size_t RS_LDS = 2u * 2u * 128u * LDS_STRIDE * 2u;  // 73728 B

    char* w = (char*)d_ws;
    const size_t NEED = (size_t)153 * (1 << 20);

    if (ws_size >= NEED) {
        unsigned short* encB  = (unsigned short*)(w);                           // 128 MB
        unsigned short* lgB   = (unsigned short*)(w);                           // 16.4 MB, reuses dead encB
        unsigned short* WiB   = (unsigned short*)(w + (size_t)128 * (1 << 20)); // 2 MB
        float* hproj          = (float*)(w + (size_t)130 * (1 << 20));          // 1 MB
        float* gh             = (float*)(w + (size_t)131 * (1 << 20));          // 3 MB
        float* epart          = (float*)(w + (size_t)134 * (1 << 20));          // 4 MB [b][t][16]
        float* pc             = (float*)(w + (size_t)138 * (1 << 20));          // 4 MB
        unsigned short* xB    = (unsigned short*)(w + (size_t)142 * (1 << 20)); // 1 MB
        float* gi             = (float*)(w + (size_t)143 * (1 << 20));          // 3 MB
        unsigned short* hnB   = (unsigned short*)(w + (size_t)146 * (1 << 20)); // 0.5 MB
        float* lsepart        = (float*)(w + (size_t)147 * (1 << 20));          // 0.5 MB
        float* lse            = (float*)(w + (size_t)148 * (1 << 20));          // 1 KB

        prep_all<<<2048, 256, 0, stream>>>(enc, encB, W_i2h, WiB, emb, tokens, xB);
        gemm_h2<<<64, 256, RS_LDS, stream>>>(h0, W_h2h, W_hh, b_h2h, b_hh, hproj, gh);
        gemm8p_e<<<1024, 512, 0, stream>>>(encB, WiB, hproj, w_score, epart);
        softmax_alpha<<<256, 256, 0, stream>>>(epart, alpha, 16);
        ctx_part_bf<<<dim3(256, 4), 128, 0, stream>>>(alpha, encB, pc);
        ctx_fin<<<256, 256, 0, stream>>>(pc, xB);
        gemm_rs<0, true, false><<<48, 256, RS_LDS, stream>>>(xB, W_ih, b_ih, gi,
            nullptr, nullptr, nullptr, nullptr, nullptr, 256, 3072, 2048);
        gru_kernel<<<1024, 256, 0, stream>>>(gi, gh, h0, hnew, hnB);
        // encB is dead past this point; lgB overlays it
        gemm_rs<2, true, false><<<500, 256, RS_LDS, stream>>>(hnB, W_out, b_out, nullptr,
            lgB, nullptr, nullptr, nullptr, lsepart, 256, 32000, 1024);
        lse_reduce<<<256, 64, 0, stream>>>(lsepart, lse, 250);
        lsub_bf<<<4000, 256, 0, stream>>>(lgB, lse, out);
    } else {
        // fallback: reg-staged everywhere (ws >= 36 MB)
        unsigned short* WiB   = (unsigned short*)(w);
        float* hproj          = (float*)(w + (size_t)2  * (1 << 20));
        float* gh             = (float*)(w + (size_t)3  * (1 << 20));
        float* epart          = (float*)(w + (size_t)6  * (1 << 20));
        float* pc             = (float*)(w + (size_t)8  * (1 << 20));
        unsigned short* xB    = (unsigned short*)(w + (size_t)12 * (1 << 20));
        float* gi             = (float*)(w + (size_t)13 * (1 << 20));
        unsigned short* hnB   = (unsigned short*)(w + (size_t)16 * (1 << 20));
        float* lsepart        = (float*)(w + (size_t)17 * (1 << 20));
        float* lse            = (float*)(w + (size_t)18 * (1 << 20));
        unsigned short* lgB   = (unsigned short*)(w + (size_t)19 * (1 << 20));

        prep_kernel<<<1280, 256, 0, stream>>>(W_i2h, WiB, emb, tokens, xB);
        gemm_h2<<<64, 256, RS_LDS, stream>>>(h0, W_h2h, W_hh, b_h2h, b_hh, hproj, gh);
        gemm_rs<1, false, true><<<4096, 256, RS_LDS, stream>>>(enc, WiB, nullptr, nullptr,
            nullptr, hproj, w_score, epart, nullptr, 65536, 1024, 1024);
        softmax_alpha<<<256, 256, 0, stream>>>(epart, alpha, 8);
        ctx_part<<<dim3(256, 4), 256, 0, stream>>>(alpha, enc, pc);
        ctx_fin<<<256, 256, 0, stream>>>(pc, xB);
        gemm_rs<0, true, false><<<48, 256, RS_LDS, stream>>>(xB, W_ih, b_ih, gi,
            nullptr, nullptr, nullptr, nullptr, nullptr, 256, 3072, 2048);
        gru_kernel<<<1024, 256, 0, stream>>>(gi, gh, h0, hnew, hnB);
        gemm_rs<2, true, false><<<500, 256, RS_LDS, stream>>>(hnB, W_out, b_out, nullptr,
            lgB, nullptr, nullptr, nullptr, lsepart, 256, 32000, 1024);
        lse_reduce<<<256, 64, 0, stream>>>(lsepart, lse, 250);
        lsub_bf<<<4000, 256, 0, stream>>>(lgB, lse, out);
    }
}

// Round 11
// 415.557 us; speedup vs baseline: 1.4408x; 1.1533x over previous
//
#include <hip/hip_runtime.h>
#include <hip/hip_bf16.h>

typedef __attribute__((ext_vector_type(8))) short bf16x8;
typedef __attribute__((ext_vector_type(4))) float f32x4;
typedef __attribute__((ext_vector_type(4))) int i32x4;
typedef __attribute__((ext_vector_type(4))) unsigned short u16x4;
typedef __attribute__((ext_vector_type(8))) unsigned short u16x8;

#define LDS_STRIDE 72   // reg-staged kernels

__device__ __forceinline__ unsigned short f2bf(float f) {
    __hip_bfloat16 h = __float2bfloat16(f);
    unsigned short u; __builtin_memcpy(&u, &h, 2); return u;
}
__device__ __forceinline__ float bf2f(unsigned short u) {
    union { unsigned u; float f; } v; v.u = ((unsigned)u) << 16; return v.f;
}
__device__ __forceinline__ float fast_sigmoid(float x) { return 1.f / (1.f + __expf(-x)); }
__device__ __forceinline__ float fast_tanh(float x)    { return 1.f - 2.f / (__expf(2.f * x) + 1.f); }

#define GLOAD_LDS16(gp, lp) __builtin_amdgcn_global_load_lds( \
    (const __attribute__((address_space(1))) void*)(gp), \
    (__attribute__((address_space(3))) void*)(lp), 16, 0, 0)

// ===========================================================================
// 8-phase 256x256 e-GEMM — UNCHANGED from r9 (verified passing, 205 us).
// ===========================================================================

#define STA(LB, HF, PTR) do { \
    GLOAD_LDS16((PTR), &AL[LB][HF][ldsrow][0]); \
    GLOAD_LDS16((PTR) + 65536, &AL[LB][HF][64 + ldsrow][0]); \
} while (0)

#define STB(LB, HF, PTR) do { \
    GLOAD_LDS16((PTR), &BL[LB][HF][ldsrow][0]); \
    GLOAD_LDS16((PTR) + 65536, &BL[LB][HF][64 + ldsrow][0]); \
} while (0)

#define LDA(DST, BUF, MH, KS) do { \
    const int c_ = ((KS)*32 + fg*8) ^ swzr; \
    _Pragma("unroll") \
    for (int mi = 0; mi < 4; ++mi) \
        DST[mi] = *(const bf16x8*)&AL[BUF][wr][(MH)*64 + mi*16 + fr][c_]; \
} while (0)

#define LDB(DST, BUF, KS) do { \
    const int c_ = ((KS)*32 + fg*8) ^ swzr; \
    _Pragma("unroll") \
    for (int ni = 0; ni < 4; ++ni) \
        DST[ni] = *(const bf16x8*)&BL[BUF][bh][br0 + ni*16 + fr][c_]; \
} while (0)

#define MM(AV, BV, MH) do { \
    _Pragma("unroll") \
    for (int mi = 0; mi < 4; ++mi) \
        _Pragma("unroll") \
        for (int ni = 0; ni < 4; ++ni) \
            acc[(MH)*4 + mi][ni] = __builtin_amdgcn_mfma_f32_16x16x32_bf16( \
                AV[mi], BV[ni], acc[(MH)*4 + mi][ni], 0, 0, 0); \
} while (0)

#define SP1 __builtin_amdgcn_s_setprio(1)
#define SP0 __builtin_amdgcn_s_setprio(0)
#define BAR asm volatile("s_barrier" ::: "memory")
#define VMC8 asm volatile("s_waitcnt vmcnt(8)" ::: "memory")
#define VMC0 asm volatile("s_waitcnt vmcnt(0)" ::: "memory")

__global__ __launch_bounds__(512, 1)
void gemm8p_e(const unsigned short* __restrict__ Ag, const unsigned short* __restrict__ Bg,
              const float* __restrict__ hproj, const float* __restrict__ wscore,
              float* __restrict__ epart)
{
    const int tid = threadIdx.x;
    const int lane = tid & 63, wid = tid >> 6;
    const int fr = lane & 15, fg = lane >> 4;
    const int wr = wid >> 2;
    const int wc = wid & 3;
    const int bh = wc >> 1, br0 = (wc & 1) * 64;

    const int cpx = (int)gridDim.x >> 3;
    const int swz = ((int)blockIdx.x & 7) * cpx + ((int)blockIdx.x >> 3);
    const int mb = swz >> 2, nb = swz & 3;
    const int m0 = mb << 8, n0 = nb << 8;

    __shared__ unsigned short AL[3][2][128][64];
    __shared__ unsigned short BL[2][2][128][64];

    const int srow = lane >> 3;
    const int scol = ((lane & 7) ^ srow) << 3;
    const int swzr = (fr & 7) << 3;
    const int ldsrow = wid * 8;

    const unsigned short* pA0 = Ag + (size_t)(m0 + ldsrow + srow) * 1024 + scol;
    const unsigned short* pA1 = pA0 + (size_t)128 * 1024;
    const unsigned short* pB0 = Bg + (size_t)(n0 + ldsrow + srow) * 1024 + scol;
    const unsigned short* pB1 = pB0 + (size_t)128 * 1024;

    f32x4 acc[8][4];
#pragma unroll
    for (int i = 0; i < 8; ++i)
#pragma unroll
        for (int j = 0; j < 4; ++j) acc[i][j] = (f32x4){0.f, 0.f, 0.f, 0.f};
    bf16x8 avA[4], avB[4], bvA[4], bvB[4];

    STA(0, 0, pA0);      STA(0, 1, pA1);
    STB(0, 0, pB0);      STB(0, 1, pB1);
    STA(1, 0, pA0 + 64); STA(1, 1, pA1 + 64);
    STB(1, 0, pB0 + 64); STB(1, 1, pB1 + 64);
    VMC8;
    BAR;

#pragma unroll
    for (int t = 0; t < 16; t += 2) {
        const int tof = t * 64;
        const int a0 = t % 3, a1 = (t + 1) % 3, a2 = (t + 2) % 3, a3 = (t + 3) % 3;
        LDB(bvA, 0, 0); LDA(avA, a0, 0, 0);
        SP1; MM(avA, bvA, 0); SP0;
        LDB(bvB, 0, 1); LDA(avB, a0, 0, 1);
        if (t + 2 < 16) STA(a2, 0, pA0 + tof + 128);
        BAR;
        SP1; MM(avB, bvB, 0); SP0;
        LDA(avA, a0, 1, 0);
        if (t + 2 < 16) STA(a2, 1, pA1 + tof + 128);
        BAR;
        SP1; MM(avA, bvA, 1); SP0;
        LDA(avB, a0, 1, 1);
        if (t + 2 < 16) STB(0, 0, pB0 + tof + 128);
        BAR;
        SP1; MM(avB, bvB, 1); SP0;
        if (t + 2 < 16) { STB(0, 1, pB1 + tof + 128); VMC8; } else { VMC0; }
        BAR;
        LDB(bvA, 1, 0); LDA(avA, a1, 0, 0);
        SP1; MM(avA, bvA, 0); SP0;
        LDB(bvB, 1, 1); LDA(avB, a1, 0, 1);
        if (t + 3 < 16) STA(a3, 0, pA0 + tof + 192);
        BAR;
        SP1; MM(avB, bvB, 0); SP0;
        LDA(avA, a1, 1, 0);
        if (t + 3 < 16) STA(a3, 1, pA1 + tof + 192);
        BAR;
        SP1; MM(avA, bvA, 1); SP0;
        LDA(avB, a1, 1, 1);
        if (t + 3 < 16) STB(1, 0, pB0 + tof + 192);
        BAR;
        SP1; MM(avB, bvB, 1); SP0;
        if (t + 3 < 16) { STB(1, 1, pB1 + tof + 192); VMC8; }
        BAR;
    }

    float wsv[4];
#pragma unroll
    for (int ni = 0; ni < 4; ++ni) wsv[ni] = wscore[n0 + wc * 64 + ni * 16 + fr];
#pragma unroll
    for (int mi = 0; mi < 8; ++mi)
#pragma unroll
        for (int r = 0; r < 4; ++r) {
            const int bb = wr * 128 + mi * 16 + fg * 4 + r;
            const float* hp = hproj + (size_t)bb * 1024 + n0 + wc * 64 + fr;
            float s = 0.f;
#pragma unroll
            for (int ni = 0; ni < 4; ++ni)
                s += fast_tanh(acc[mi][ni][r] + hp[ni * 16]) * wsv[ni];
            s += __shfl_xor(s, 1); s += __shfl_xor(s, 2);
            s += __shfl_xor(s, 4); s += __shfl_xor(s, 8);
            if (fr == 0) epart[((size_t)bb * 256 + mb) * 16 + nb * 4 + wc] = s;
        }
}

// ---------------------------------------------------------------------------
// h2 body (device): C = h0 @ [W_h2h ; W_hh]^T + bias, one 128x128 tile/block.
// ---------------------------------------------------------------------------
__device__ void h2_body(char* smem, int blk, const float* __restrict__ h0,
                        const float* __restrict__ Wh2h, const float* __restrict__ Whh,
                        const float* __restrict__ bh2h, const float* __restrict__ bhh,
                        float* __restrict__ hproj, float* __restrict__ gh)
{
    const int mb = blk & 1;
    const int nbg = blk >> 1;
    const float* Bf; const float* bias; float* Cout; int Nst; int n0;
    if (nbg < 8) { Bf = Wh2h; bias = bh2h; Cout = hproj; Nst = 1024; n0 = nbg << 7; }
    else         { Bf = Whh;  bias = bhh;  Cout = gh;    Nst = 3072; n0 = (nbg - 8) << 7; }

    const int m0 = mb << 7;
    const int tid = threadIdx.x;
    const int lane = tid & 63, wid = tid >> 6;
    const int fr = lane & 15, fg = lane >> 4;
    const int srow = tid >> 1, shalf = (tid & 1) * 32;

    typedef unsigned short (*tile_t)[128][LDS_STRIDE];
    tile_t As = (tile_t)smem;
    tile_t Bs = (tile_t)(smem + 2 * 128 * LDS_STRIDE * 2);

    f32x4 acc[2][8];
#pragma unroll
    for (int i = 0; i < 2; ++i)
#pragma unroll
        for (int j = 0; j < 8; ++j) acc[i][j] = (f32x4){0.f, 0.f, 0.f, 0.f};

    float a_f[32], b_f[32];

    auto loadA = [&](int kt) {
        size_t base = (size_t)(m0 + srow) * 1024 + (size_t)kt * 64 + shalf;
#pragma unroll
        for (int j = 0; j < 8; ++j) *(f32x4*)&a_f[j * 4] = *(const f32x4*)(h0 + base + j * 4);
    };
    auto loadB = [&](int kt) {
        size_t base = (size_t)(n0 + srow) * 1024 + (size_t)kt * 64 + shalf;
#pragma unroll
        for (int j = 0; j < 8; ++j) *(f32x4*)&b_f[j * 4] = *(const f32x4*)(Bf + base + j * 4);
    };
    auto storeA = [&](int buf) {
        unsigned short t[32];
#pragma unroll
        for (int j = 0; j < 32; ++j) t[j] = f2bf(a_f[j]);
#pragma unroll
        for (int j = 0; j < 4; ++j) *(i32x4*)&As[buf][srow][shalf + j * 8] = *(i32x4*)&t[j * 8];
    };
    auto storeB = [&](int buf) {
        unsigned short t[32];
#pragma unroll
        for (int j = 0; j < 32; ++j) t[j] = f2bf(b_f[j]);
#pragma unroll
        for (int j = 0; j < 4; ++j) *(i32x4*)&Bs[buf][srow][shalf + j * 8] = *(i32x4*)&t[j * 8];
    };

    loadA(0); loadB(0);
    storeA(0); storeB(0);
    __syncthreads();

    for (int kt = 0; kt < 16; ++kt) {
        const int cur = kt & 1;
        if (kt + 1 < 16) { loadA(kt + 1); loadB(kt + 1); }
#pragma unroll
        for (int ks = 0; ks < 2; ++ks) {
            bf16x8 av[2], bv[8];
#pragma unroll
            for (int mi = 0; mi < 2; ++mi)
                av[mi] = *(const bf16x8*)&As[cur][wid * 32 + mi * 16 + fr][ks * 32 + fg * 8];
#pragma unroll
            for (int ni = 0; ni < 8; ++ni)
                bv[ni] = *(const bf16x8*)&Bs[cur][ni * 16 + fr][ks * 32 + fg * 8];
#pragma unroll
            for (int mi = 0; mi < 2; ++mi)
#pragma unroll
                for (int ni = 0; ni < 8; ++ni)
                    acc[mi][ni] = __builtin_amdgcn_mfma_f32_16x16x32_bf16(av[mi], bv[ni], acc[mi][ni], 0, 0, 0);
        }
        if (kt + 1 < 16) { storeA(cur ^ 1); storeB(cur ^ 1); }
        __syncthreads();
    }

#pragma unroll
    for (int mi = 0; mi < 2; ++mi)
#pragma unroll
        for (int r = 0; r < 4; ++r) {
            const int m = m0 + wid * 32 + mi * 16 + fg * 4 + r;
#pragma unroll
            for (int ni = 0; ni < 8; ++ni) {
                const int col = n0 + ni * 16 + fr;
                Cout[(size_t)m * Nst + col] = acc[mi][ni][r] + bias[col];
            }
        }
}

// ---------------------------------------------------------------------------
// FUSED prep + h2: blocks 0..63 -> h2 GEMM; blocks 64.. -> enc/W_i2h/emb prep.
// ---------------------------------------------------------------------------
__global__ __launch_bounds__(256, 2)
void prep_h2(const float* __restrict__ enc, unsigned short* __restrict__ encB,
             const float* __restrict__ Wi2h, unsigned short* __restrict__ WiB,
             const float* __restrict__ emb, const int* __restrict__ tokens,
             unsigned short* __restrict__ xB,
             const float* __restrict__ h0,
             const float* __restrict__ Wh2h, const float* __restrict__ Whh,
             const float* __restrict__ bh2h, const float* __restrict__ bhh,
             float* __restrict__ hproj, float* __restrict__ gh)
{
    extern __shared__ char smem[];
    if (blockIdx.x < 64) {
        h2_body(smem, blockIdx.x, h0, Wh2h, Whh, bh2h, bhh, hproj, gh);
        return;
    }
    const int ENC4 = 16777216, WI4 = 262144, EMB4 = 65536;
    const int total = ENC4 + WI4 + EMB4;
    const int stride = ((int)gridDim.x - 64) * 256;
    for (int i = ((int)blockIdx.x - 64) * 256 + (int)threadIdx.x; i < total; i += stride) {
        f32x4 v; unsigned short* dst;
        if (i < ENC4) {
            v = *(const f32x4*)(enc + (size_t)i * 4);
            dst = encB + (size_t)i * 4;
        } else if (i < ENC4 + WI4) {
            int j = i - ENC4;
            v = *(const f32x4*)(Wi2h + (size_t)j * 4);
            dst = WiB + (size_t)j * 4;
        } else {
            int j = i - ENC4 - WI4;
            int b = j >> 8, h4 = j & 255;
            v = *(const f32x4*)(emb + (size_t)tokens[b] * 1024 + h4 * 4);
            dst = xB + (size_t)b * 2048 + 1024 + h4 * 4;
        }
        u16x4 o;
#pragma unroll
        for (int j = 0; j < 4; ++j) o[j] = f2bf(v[j]);
        *(u16x4*)dst = o;
    }
}

// standalone h2 (fallback path)
__global__ __launch_bounds__(256, 2)
void gemm_h2(const float* __restrict__ h0,
             const float* __restrict__ Wh2h, const float* __restrict__ Whh,
             const float* __restrict__ bh2h, const float* __restrict__ bhh,
             float* __restrict__ hproj, float* __restrict__ gh)
{
    extern __shared__ char smem[];
    h2_body(smem, blockIdx.x, h0, Wh2h, Whh, bh2h, bhh, hproj, gh);
}

// ---------------------------------------------------------------------------
// gi GEMM with 4-way K-split: gip[s][256][3072] = xB[:, s*512:(s+1)*512] @
// W_ih[:, s*512:(s+1)*512]^T. 192 blocks. No bias (added in gru4).
// ---------------------------------------------------------------------------
__global__ __launch_bounds__(256, 2)
void gemm_gi(const unsigned short* __restrict__ xB, const float* __restrict__ Wih,
             float* __restrict__ gip)
{
    const int s = blockIdx.x / 48;
    const int b = blockIdx.x % 48;
    const int mb = b & 1, nb = b >> 1;
    const int m0 = mb << 7, n0 = nb << 7;
    const int kbase = s * 512;
    const int tid = threadIdx.x;
    const int lane = tid & 63, wid = tid >> 6;
    const int fr = lane & 15, fg = lane >> 4;
    const int srow = tid >> 1, shalf = (tid & 1) * 32;

    extern __shared__ char smem[];
    typedef unsigned short (*tile_t)[128][LDS_STRIDE];
    tile_t As = (tile_t)smem;
    tile_t Bs = (tile_t)(smem + 2 * 128 * LDS_STRIDE * 2);

    f32x4 acc[2][8];
#pragma unroll
    for (int i = 0; i < 2; ++i)
#pragma unroll
        for (int j = 0; j < 8; ++j) acc[i][j] = (f32x4){0.f, 0.f, 0.f, 0.f};

    unsigned short a_b[32]; float b_f[32];

    auto loadA = [&](int kt) {
        size_t base = (size_t)(m0 + srow) * 2048 + kbase + (size_t)kt * 64 + shalf;
#pragma unroll
        for (int j = 0; j < 4; ++j) *(i32x4*)&a_b[j * 8] = *(const i32x4*)(xB + base + j * 8);
    };
    auto loadB = [&](int kt) {
        size_t base = (size_t)(n0 + srow) * 2048 + kbase + (size_t)kt * 64 + shalf;
#pragma unroll
        for (int j = 0; j < 8; ++j) *(f32x4*)&b_f[j * 4] = *(const f32x4*)(Wih + base + j * 4);
    };
    auto storeA = [&](int buf) {
#pragma unroll
        for (int j = 0; j < 4; ++j) *(i32x4*)&As[buf][srow][shalf + j * 8] = *(i32x4*)&a_b[j * 8];
    };
    auto storeB = [&](int buf) {
        unsigned short t[32];
#pragma unroll
        for (int j = 0; j < 32; ++j) t[j] = f2bf(b_f[j]);
#pragma unroll
        for (int j = 0; j < 4; ++j) *(i32x4*)&Bs[buf][srow][shalf + j * 8] = *(i32x4*)&t[j * 8];
    };

    loadA(0); loadB(0);
    storeA(0); storeB(0);
    __syncthreads();

    for (int kt = 0; kt < 8; ++kt) {
        const int cur = kt & 1;
        if (kt + 1 < 8) { loadA(kt + 1); loadB(kt + 1); }
#pragma unroll
        for (int ks = 0; ks < 2; ++ks) {
            bf16x8 av[2], bv[8];
#pragma unroll
            for (int mi = 0; mi < 2; ++mi)
                av[mi] = *(const bf16x8*)&As[cur][wid * 32 + mi * 16 + fr][ks * 32 + fg * 8];
#pragma unroll
            for (int ni = 0; ni < 8; ++ni)
                bv[ni] = *(const bf16x8*)&Bs[cur][ni * 16 + fr][ks * 32 + fg * 8];
#pragma unroll
            for (int mi = 0; mi < 2; ++mi)
#pragma unroll
                for (int ni = 0; ni < 8; ++ni)
                    acc[mi][ni] = __builtin_amdgcn_mfma_f32_16x16x32_bf16(av[mi], bv[ni], acc[mi][ni], 0, 0, 0);
        }
        if (kt + 1 < 8) { storeA(cur ^ 1); storeB(cur ^ 1); }
        __syncthreads();
    }

    float* Cs = gip + (size_t)s * 256 * 3072;
#pragma unroll
    for (int mi = 0; mi < 2; ++mi)
#pragma unroll
        for (int r = 0; r < 4; ++r) {
            const int m = m0 + wid * 32 + mi * 16 + fg * 4 + r;
#pragma unroll
            for (int ni = 0; ni < 8; ++ni) {
                const int col = n0 + ni * 16 + fr;
                Cs[(size_t)m * 3072 + col] = acc[mi][ni][r];
            }
        }
}

// ---------------------------------------------------------------------------
// Reg-staged GEMM — fallback e-GEMM (EPI1), gi fallback (EPI0), logits (EPI2).
// ---------------------------------------------------------------------------
template<int EPI, bool ABF, bool BBF>
__global__ __launch_bounds__(256, 2)
void gemm_rs(const void* __restrict__ Agv, const void* __restrict__ Bgv,
             const float* __restrict__ bias, float* __restrict__ Cout,
             unsigned short* __restrict__ CoutB,
             const float* __restrict__ hproj, const float* __restrict__ wscore,
             float* __restrict__ epart, float* __restrict__ lsepart,
             int M, int N, int K)
{
    const int nbn = N >> 7;
    const int nmb = M >> 7;
    int mb, nb;
    if (EPI == 1) {
        int cpx = gridDim.x >> 3;
        int bp = (blockIdx.x & 7) * cpx + (blockIdx.x >> 3);
        mb = bp / nbn; nb = bp % nbn;
    } else {
        mb = blockIdx.x % nmb; nb = blockIdx.x / nmb;
    }
    const int m0 = mb << 7, n0 = nb << 7;
    const int tid = threadIdx.x;
    const int lane = tid & 63, wid = tid >> 6;
    const int fr = lane & 15, fg = lane >> 4;
    const int srow = tid >> 1, shalf = (tid & 1) * 32;

    extern __shared__ char smem[];
    typedef unsigned short (*tile_t)[128][LDS_STRIDE];
    tile_t As = (tile_t)smem;
    tile_t Bs = (tile_t)(smem + 2 * 128 * LDS_STRIDE * 2);

    const float* Af = (const float*)Agv;
    const unsigned short* Ab = (const unsigned short*)Agv;
    const float* Bf = (const float*)Bgv;
    const unsigned short* Bb = (const unsigned short*)Bgv;

    f32x4 acc[2][8];
#pragma unroll
    for (int i = 0; i < 2; ++i)
#pragma unroll
        for (int j = 0; j < 8; ++j) acc[i][j] = (f32x4){0.f, 0.f, 0.f, 0.f};

    float a_f[32]; unsigned short a_b[32];
    float b_f[32]; unsigned short b_b[32];

    auto loadA = [&](int kt) {
        size_t base = (size_t)(m0 + srow) * K + (size_t)kt * 64 + shalf;
        if (ABF) {
#pragma unroll
            for (int j = 0; j < 4; ++j) *(i32x4*)&a_b[j * 8] = *(const i32x4*)(Ab + base + j * 8);
        } else {
#pragma unroll
            for (int j = 0; j < 8; ++j) *(f32x4*)&a_f[j * 4] = *(const f32x4*)(Af + base + j * 4);
        }
    };
    auto loadB = [&](int kt) {
        size_t base = (size_t)(n0 + srow) * K + (size_t)kt * 64 + shalf;
        if (BBF) {
#pragma unroll
            for (int j = 0; j < 4; ++j) *(i32x4*)&b_b[j * 8] = *(const i32x4*)(Bb + base + j * 8);
        } else {
#pragma unroll
            for (int j = 0; j < 8; ++j) *(f32x4*)&b_f[j * 4] = *(const f32x4*)(Bf + base + j * 4);
        }
    };
    auto storeA = [&](int buf) {
        unsigned short tA[32];
        if (ABF) {
#pragma unroll
            for (int j = 0; j < 32; ++j) tA[j] = a_b[j];
        } else {
#pragma unroll
            for (int j = 0; j < 32; ++j) tA[j] = f2bf(a_f[j]);
        }
#pragma unroll
        for (int j = 0; j < 4; ++j) *(i32x4*)&As[buf][srow][shalf + j * 8] = *(i32x4*)&tA[j * 8];
    };
    auto storeB = [&](int buf) {
        unsigned short tB[32];
        if (BBF) {
#pragma unroll
            for (int j = 0; j < 32; ++j) tB[j] = b_b[j];
        } else {
#pragma unroll
            for (int j = 0; j < 32; ++j) tB[j] = f2bf(b_f[j]);
        }
#pragma unroll
        for (int j = 0; j < 4; ++j) *(i32x4*)&Bs[buf][srow][shalf + j * 8] = *(i32x4*)&tB[j * 8];
    };

    const int nkt = K >> 6;

    loadA(0); loadB(0);
    storeA(0); storeB(0);
    __syncthreads();

    for (int kt = 0; kt < nkt; ++kt) {
        const int cur = kt & 1;
        if (kt + 1 < nkt) { loadA(kt + 1); loadB(kt + 1); }
#pragma unroll
        for (int ks = 0; ks < 2; ++ks) {
            bf16x8 av[2], bv[8];
#pragma unroll
            for (int mi = 0; mi < 2; ++mi)
                av[mi] = *(const bf16x8*)&As[cur][wid * 32 + mi * 16 + fr][ks * 32 + fg * 8];
#pragma unroll
            for (int ni = 0; ni < 8; ++ni)
                bv[ni] = *(const bf16x8*)&Bs[cur][ni * 16 + fr][ks * 32 + fg * 8];
#pragma unroll
            for (int mi = 0; mi < 2; ++mi)
#pragma unroll
                for (int ni = 0; ni < 8; ++ni)
                    acc[mi][ni] = __builtin_amdgcn_mfma_f32_16x16x32_bf16(av[mi], bv[ni], acc[mi][ni], 0, 0, 0);
        }
        if (kt + 1 < nkt) { storeA(cur ^ 1); storeB(cur ^ 1); }
        __syncthreads();
    }

    if (EPI == 0) {
#pragma unroll
        for (int mi = 0; mi < 2; ++mi)
#pragma unroll
            for (int r = 0; r < 4; ++r) {
                const int m = m0 + wid * 32 + mi * 16 + fg * 4 + r;
#pragma unroll
                for (int ni = 0; ni < 8; ++ni) {
                    const int col = n0 + ni * 16 + fr;
                    Cout[(size_t)m * N + col] = acc[mi][ni][r] + bias[col];
                }
            }
    } else if (EPI == 1) {
        float wsv[8];
#pragma unroll
        for (int ni = 0; ni < 8; ++ni) wsv[ni] = wscore[n0 + ni * 16 + fr];
#pragma unroll
        for (int mi = 0; mi < 2; ++mi)
#pragma unroll
            for (int r = 0; r < 4; ++r) {
                const int m = m0 + wid * 32 + mi * 16 + fg * 4 + r;
                const int bb = m & 255, tt = m >> 8;
                const float* hp = hproj + (size_t)bb * 1024 + n0 + fr;
                float s = 0.f;
#pragma unroll
                for (int ni = 0; ni < 8; ++ni)
                    s += fast_tanh(acc[mi][ni][r] + hp[ni * 16]) * wsv[ni];
                s += __shfl_xor(s, 1); s += __shfl_xor(s, 2);
                s += __shfl_xor(s, 4); s += __shfl_xor(s, 8);
                if (fr == 0) epart[((size_t)bb * 256 + tt) * 8 + nb] = s;
            }
    } else {  // EPI 2: bf16 logits + (max,sumexp) partials
#pragma unroll
        for (int mi = 0; mi < 2; ++mi)
#pragma unroll
            for (int r = 0; r < 4; ++r) {
                const int m = m0 + wid * 32 + mi * 16 + fg * 4 + r;
                float vv[8];
                float mx = -3.4e38f;
#pragma unroll
                for (int ni = 0; ni < 8; ++ni) {
                    const int col = n0 + ni * 16 + fr;
                    vv[ni] = acc[mi][ni][r] + bias[col];
                    CoutB[(size_t)m * N + col] = f2bf(vv[ni]);
                    mx = fmaxf(mx, vv[ni]);
                }
                mx = fmaxf(mx, __shfl_xor(mx, 1));
                mx = fmaxf(mx, __shfl_xor(mx, 2));
                mx = fmaxf(mx, __shfl_xor(mx, 4));
                mx = fmaxf(mx, __shfl_xor(mx, 8));
                float se = 0.f;
#pragma unroll
                for (int ni = 0; ni < 8; ++ni) se += __expf(vv[ni] - mx);
                se += __shfl_xor(se, 1); se += __shfl_xor(se, 2);
                se += __shfl_xor(se, 4); se += __shfl_xor(se, 8);
                if (fr == 0) {
                    lsepart[((size_t)m * nbn + nb) * 2]     = mx;
                    lsepart[((size_t)m * nbn + nb) * 2 + 1] = se;
                }
            }
    }
}

// fallback prep: W_i2h conv + emb gather only
__global__ void prep_kernel(const float* __restrict__ Wi2h, unsigned short* __restrict__ WiB,
                            const float* __restrict__ emb, const int* __restrict__ tokens,
                            unsigned short* __restrict__ xB)
{
    int i = blockIdx.x * 256 + threadIdx.x;
    if (i < 262144) {
        f32x4 v = *(const f32x4*)(Wi2h + (size_t)i * 4);
        u16x4 o;
#pragma unroll
        for (int j = 0; j < 4; ++j) o[j] = f2bf(v[j]);
        *(u16x4*)(WiB + (size_t)i * 4) = o;
    } else {
        int j = i - 262144;
        int b = j >> 8, h4 = j & 255;
        int tok = tokens[b];
        f32x4 v = *(const f32x4*)(emb + (size_t)tok * 1024 + h4 * 4);
        u16x4 o;
#pragma unroll
        for (int jj = 0; jj < 4; ++jj) o[jj] = f2bf(v[jj]);
        *(u16x4*)(xB + (size_t)b * 2048 + 1024 + h4 * 4) = o;
    }
}

// softmax over t per batch b; epart is [b][t][pw] partials
__global__ __launch_bounds__(256) void softmax_alpha(const float* __restrict__ epart,
                                                     float* __restrict__ alpha, int pw)
{
    const int b = blockIdx.x, t = threadIdx.x;
    const int lane = t & 63, w = t >> 6;
    const float* ep = epart + ((size_t)b * 256 + t) * pw;
    float s = 0.f;
    for (int j = 0; j < pw; ++j) s += ep[j];
    __shared__ float rmax[4], rsum[4];
    float mx = s;
#pragma unroll
    for (int d = 1; d < 64; d <<= 1) mx = fmaxf(mx, __shfl_xor(mx, d));
    if (lane == 0) rmax[w] = mx;
    __syncthreads();
    mx = fmaxf(fmaxf(rmax[0], rmax[1]), fmaxf(rmax[2], rmax[3]));
    float p = __expf(s - mx);
    float sm = p;
#pragma unroll
    for (int d = 1; d < 64; d <<= 1) sm += __shfl_xor(sm, d);
    if (lane == 0) rsum[w] = sm;
    __syncthreads();
    sm = rsum[0] + rsum[1] + rsum[2] + rsum[3];
    alpha[(size_t)b * 256 + t] = p / sm;
}

// context partials from bf16 enc
__global__ __launch_bounds__(128) void ctx_part_bf(const float* __restrict__ alpha,
                                                   const unsigned short* __restrict__ encB,
                                                   float* __restrict__ pc)
{
    const int b = blockIdx.x, tc = blockIdx.y;
    const int h8 = threadIdx.x;
    const float* al = alpha + (size_t)b * 256 + tc * 64;
    float acc[8];
#pragma unroll
    for (int j = 0; j < 8; ++j) acc[j] = 0.f;
#pragma unroll 4
    for (int i = 0; i < 64; ++i) {
        float a = al[i];
        u16x8 e = *(const u16x8*)(encB + ((size_t)(tc * 64 + i) * 256 + b) * 1024 + h8 * 8);
#pragma unroll
        for (int j = 0; j < 8; ++j) acc[j] += bf2f(e[j]) * a;
    }
    float* d = pc + ((size_t)tc * 256 + b) * 1024 + h8 * 8;
    *(f32x4*)d = *(f32x4*)&acc[0];
    *(f32x4*)(d + 4) = *(f32x4*)&acc[4];
}

// fallback f32 ctx_part
__global__ __launch_bounds__(256) void ctx_part(const float* __restrict__ alpha,
                                                const float* __restrict__ enc,
                                                float* __restrict__ pc)
{
    const int b = blockIdx.x, tc = blockIdx.y;
    const int h4 = threadIdx.x;
    const float* al = alpha + (size_t)b * 256 + tc * 64;
    f32x4 acc = {0.f, 0.f, 0.f, 0.f};
#pragma unroll 4
    for (int i = 0; i < 64; ++i) {
        float a = al[i];
        f32x4 e = *(const f32x4*)(enc + ((size_t)(tc * 64 + i) * 256 + b) * 1024 + h4 * 4);
        acc += e * a;
    }
    *(f32x4*)(pc + ((size_t)tc * 256 + b) * 1024 + h4 * 4) = acc;
}

// reduce context partials -> x_bf16[:,0:1024]
__global__ void ctx_fin(const float* __restrict__ pc, unsigned short* __restrict__ xB)
{
    const int b = blockIdx.x, h4 = threadIdx.x;
    f32x4 c = {0.f, 0.f, 0.f, 0.f};
#pragma unroll
    for (int tc = 0; tc < 4; ++tc)
        c += *(const f32x4*)(pc + ((size_t)tc * 256 + b) * 1024 + h4 * 4);
    u16x4 o;
#pragma unroll
    for (int j = 0; j < 4; ++j) o[j] = f2bf(c[j]);
    *(u16x4*)(xB + (size_t)b * 2048 + h4 * 4) = o;
}

// GRU elementwise with 4-way gi split sum + b_ih (PyTorch gate order r,z,n)
__global__ void gru4_kernel(const float* __restrict__ gip, const float* __restrict__ gh,
                            const float* __restrict__ bih, const float* __restrict__ h0,
                            float* __restrict__ hnew, unsigned short* __restrict__ hnB)
{
    int idx = blockIdx.x * 256 + threadIdx.x;
    int b = idx >> 10, h = idx & 1023;
    size_t gb = (size_t)b * 3072;
    const size_t S = (size_t)256 * 3072;
    float g0 = gip[gb + h]        + gip[S + gb + h]        + gip[2*S + gb + h]        + gip[3*S + gb + h]        + bih[h];
    float g1 = gip[gb + 1024 + h] + gip[S + gb + 1024 + h] + gip[2*S + gb + 1024 + h] + gip[3*S + gb + 1024 + h] + bih[1024 + h];
    float g2 = gip[gb + 2048 + h] + gip[S + gb + 2048 + h] + gip[2*S + gb + 2048 + h] + gip[3*S + gb + 2048 + h] + bih[2048 + h];
    float r = fast_sigmoid(g0 + gh[gb + h]);
    float z = fast_sigmoid(g1 + gh[gb + 1024 + h]);
    float n = fast_tanh   (g2 + r * gh[gb + 2048 + h]);
    float hp = h0[idx];
    float hn = (1.f - z) * n + z * hp;
    hnew[idx] = hn;
    hnB[idx] = f2bf(hn);
}

// fallback GRU (single gi incl. bias)
__global__ void gru_kernel(const float* __restrict__ gi, const float* __restrict__ gh,
                           const float* __restrict__ h0, float* __restrict__ hnew,
                           unsigned short* __restrict__ hnB)
{
    int idx = blockIdx.x * 256 + threadIdx.x;
    int b = idx >> 10, h = idx & 1023;
    size_t gb = (size_t)b * 3072;
    float r = fast_sigmoid(gi[gb + h]        + gh[gb + h]);
    float z = fast_sigmoid(gi[gb + 1024 + h] + gh[gb + 1024 + h]);
    float n = fast_tanh   (gi[gb + 2048 + h] + r * gh[gb + 2048 + h]);
    float hp = h0[idx];
    float hn = (1.f - z) * n + z * hp;
    hnew[idx] = hn;
    hnB[idx] = f2bf(hn);
}

// fused lse reduce + log-softmax subtract: one block per row m.
__global__ __launch_bounds__(256) void lse_sub(const float* __restrict__ lsepart,
                                               const unsigned short* __restrict__ lgB,
                                               float* __restrict__ out)
{
    const int m = blockIdx.x, tid = threadIdx.x;
    const int lane = tid & 63, w = tid >> 6;
    float mx = -3.4e38f, s = 0.f;
    if (tid < 250) {
        mx = lsepart[((size_t)m * 250 + tid) * 2];
        s  = lsepart[((size_t)m * 250 + tid) * 2 + 1];
    }
#pragma unroll
    for (int d = 1; d < 64; d <<= 1) {
        float om = __shfl_xor(mx, d), os = __shfl_xor(s, d);
        float nm = fmaxf(mx, om);
        s = s * __expf(mx - nm) + os * __expf(om - nm);
        mx = nm;
    }
    __shared__ float smx[4], ssm[4];
    if (lane == 0) { smx[w] = mx; ssm[w] = s; }
    __syncthreads();
    float fm = smx[0], fs = ssm[0];
#pragma unroll
    for (int i = 1; i < 4; ++i) {
        float nm = fmaxf(fm, smx[i]);
        fs = fs * __expf(fm - nm) + ssm[i] * __expf(smx[i] - nm);
        fm = nm;
    }
    const float lse = fm + __logf(fs);
    const unsigned short* lrow = lgB + (size_t)m * 32000;
    float* orow = out + (size_t)m * 32000;
    for (int j = tid; j < 4000; j += 256) {
        u16x8 v = *(const u16x8*)(lrow + (size_t)j * 8);
        f32x4 o0, o1;
#pragma unroll
        for (int k = 0; k < 4; ++k) o0[k] = bf2f(v[k]) - lse;
#pragma unroll
        for (int k = 0; k < 4; ++k) o1[k] = bf2f(v[4 + k]) - lse;
        *(f32x4*)(orow + (size_t)j * 8) = o0;
        *(f32x4*)(orow + (size_t)j * 8 + 4) = o1;
    }
}

// fallback lse/lsub pair
__global__ void lse_reduce(const float* __restrict__ lsepart, float* __restrict__ lse, int nbn)
{
    const int m = blockIdx.x, l = threadIdx.x;
    float mx = -3.4e38f, s = 0.f;
    for (int p = l; p < nbn; p += 64) {
        float pm = lsepart[((size_t)m * nbn + p) * 2];
        float ps = lsepart[((size_t)m * nbn + p) * 2 + 1];
        float nm = fmaxf(mx, pm);
        s = s * __expf(mx - nm) + ps * __expf(pm - nm);
        mx = nm;
    }
#pragma unroll
    for (int d = 1; d < 64; d <<= 1) {
        float om = __shfl_xor(mx, d), os = __shfl_xor(s, d);
        float nm = fmaxf(mx, om);
        s = s * __expf(mx - nm) + os * __expf(om - nm);
        mx = nm;
    }
    if (l == 0) lse[m] = mx + __logf(s);
}

__global__ void lsub_bf(const unsigned short* __restrict__ lgB,
                        const float* __restrict__ lse, float* __restrict__ out)
{
    int f = blockIdx.x * 256 + threadIdx.x;
    float l = lse[f / 4000];
    u16x8 v = *(const u16x8*)(lgB + (size_t)f * 8);
    float* o = out + (size_t)f * 8;
    f32x4 o0, o1;
#pragma unroll
    for (int j = 0; j < 4; ++j) o0[j] = bf2f(v[j]) - l;
#pragma unroll
    for (int j = 0; j < 4; ++j) o1[j] = bf2f(v[4 + j]) - l;
    *(f32x4*)o = o0;
    *(f32x4*)(o + 4) = o1;
}

// ---------------------------------------------------------------------------
extern "C" void kernel_launch(void* const* d_in, const int* in_sizes, int n_in,
                              void* d_out, int out_size, void* d_ws, size_t ws_size,
                              hipStream_t stream)
{
    const int*   tokens  = (const int*)  d_in[0];
    const float* h0      = (const float*)d_in[1];
    const float* enc     = (const float*)d_in[2];
    const float* emb     = (const float*)d_in[3];
    const float* W_i2h   = (const float*)d_in[4];
    const float* W_h2h   = (const float*)d_in[5];
    const float* b_h2h   = (const float*)d_in[6];
    const float* w_score = (const float*)d_in[7];
    const float* W_ih    = (const float*)d_in[8];
    const float* b_ih    = (const float*)d_in[9];
    const float* W_hh    = (const float*)d_in[10];
    const float* b_hh    = (const float*)d_in[11];
    const float* W_out   = (const float*)d_in[12];
    const float* b_out   = (const float*)d_in[13];

    float* out   = (float*)d_out;
    float* hnew  = out + (size_t)256 * 32000;
    float* alpha = hnew + 256 * 1024;

    const size_t RS_LDS = 2u * 2u * 128u * LDS_STRIDE * 2u;  // 73728 B

    char* w = (char*)d_ws;
    const size_t NEED = (size_t)153 * (1 << 20);

    if (ws_size >= NEED) {
        unsigned short* encB  = (unsigned short*)(w);                           // 128 MB
        unsigned short* lgB   = (unsigned short*)(w);                           // 16.4 MB, overlays dead encB
        float* gip            = (float*)(w + (size_t)32 * (1 << 20));           // 12 MB [4][256][3072], overlays dead encB (disjoint from lgB)
        unsigned short* WiB   = (unsigned short*)(w + (size_t)128 * (1 << 20)); // 2 MB
        float* hproj          = (float*)(w + (size_t)130 * (1 << 20));          // 1 MB
        float* gh             = (float*)(w + (size_t)131 * (1 << 20));          // 3 MB
        float* epart          = (float*)(w + (size_t)134 * (1 << 20));          // 4 MB [b][t][16]
        float* pc             = (float*)(w + (size_t)138 * (1 << 20));          // 4 MB
        unsigned short* xB    = (unsigned short*)(w + (size_t)142 * (1 << 20)); // 1 MB
        unsigned short* hnB   = (unsigned short*)(w + (size_t)150 * (1 << 20)); // 0.5 MB
        float* lsepart        = (float*)(w + (size_t)151 * (1 << 20));          // 0.5 MB

        // prep (blocks 64..2111) + h2 GEMM (blocks 0..63) fused
        prep_h2<<<2112, 256, RS_LDS, stream>>>(enc, encB, W_i2h, WiB, emb, tokens, xB,
                                               h0, W_h2h, W_hh, b_h2h, b_hh, hproj, gh);
        gemm8p_e<<<1024, 512, 0, stream>>>(encB, WiB, hproj, w_score, epart);
        softmax_alpha<<<256, 256, 0, stream>>>(epart, alpha, 16);
        ctx_part_bf<<<dim3(256, 4), 128, 0, stream>>>(alpha, encB, pc);
        ctx_fin<<<256, 256, 0, stream>>>(pc, xB);
        // gi GEMM: 4-way K-split, 192 blocks. encB dead after ctx_part_bf;
        // gip sits at [32,44) MB inside dead encB, disjoint from xB/pc/lgB.
        gemm_gi<<<192, 256, RS_LDS, stream>>>(xB, W_ih, gip);
        gru4_kernel<<<1024, 256, 0, stream>>>(gip, gh, b_ih, h0, hnew, hnB);
        // lgB overlays encB [0,16.4) MB; gip is dead once gru4 completes
        gemm_rs<2, true, false><<<500, 256, RS_LDS, stream>>>(hnB, W_out, b_out, nullptr,
            lgB, nullptr, nullptr, nullptr, lsepart, 256, 32000, 1024);
        lse_sub<<<256, 256, 0, stream>>>(lsepart, lgB, out);
    } else {
        // fallback: reg-staged everywhere (ws >= 36 MB)
        unsigned short* WiB   = (unsigned short*)(w);
        float* hproj          = (float*)(w + (size_t)2  * (1 << 20));
        float* gh             = (float*)(w + (size_t)3  * (1 << 20));
        float* epart          = (float*)(w + (size_t)6  * (1 << 20));
        float* pc             = (float*)(w + (size_t)8  * (1 << 20));
        unsigned short* xB    = (unsigned short*)(w + (size_t)12 * (1 << 20));
        float* gi             = (float*)(w + (size_t)13 * (1 << 20));
        unsigned short* hnB   = (unsigned short*)(w + (size_t)16 * (1 << 20));
        float* lsepart        = (float*)(w + (size_t)17 * (1 << 20));
        float* lse            = (float*)(w + (size_t)18 * (1 << 20));
        unsigned short* lgB   = (unsigned short*)(w + (size_t)19 * (1 << 20));

        prep_kernel<<<1280, 256, 0, stream>>>(W_i2h, WiB, emb, tokens, xB);
        gemm_h2<<<64, 256, RS_LDS, stream>>>(h0, W_h2h, W_hh, b_h2h, b_hh, hproj, gh);
        gemm_rs<1, false, true><<<4096, 256, RS_LDS, stream>>>(enc, WiB, nullptr, nullptr,
            nullptr, hproj, w_score, epart, nullptr, 65536, 1024, 1024);
        softmax_alpha<<<256, 256, 0, stream>>>(epart, alpha, 8);
        ctx_part<<<dim3(256, 4), 256, 0, stream>>>(alpha, enc, pc);
        ctx_fin<<<256, 256, 0, stream>>>(pc, xB);
        gemm_rs<0, true, false><<<48, 256, RS_LDS, stream>>>(xB, W_ih, b_ih, gi,
            nullptr, nullptr, nullptr, nullptr, nullptr, 256, 3072, 2048);
        gru_kernel<<<1024, 256, 0, stream>>>(gi, gh, h0, hnew, hnB);
        gemm_rs<2, true, false><<<500, 256, RS_LDS, stream>>>(hnB, W_out, b_out, nullptr,
            lgB, nullptr, nullptr, nullptr, lsepart, 256, 32000, 1024);
        lse_reduce<<<256, 64, 0, stream>>>(lsepart, lse, 250);
        lsub_bf<<<4000, 256, 0, stream>>>(lgB, lse, out);
    }
}

// Round 12
// 413.520 us; speedup vs baseline: 1.4479x; 1.0049x over previous
//
#include <hip/hip_runtime.h>
#include <hip/hip_bf16.h>

typedef __attribute__((ext_vector_type(8))) short bf16x8;
typedef __attribute__((ext_vector_type(4))) float f32x4;
typedef __attribute__((ext_vector_type(4))) int i32x4;
typedef __attribute__((ext_vector_type(4))) unsigned short u16x4;
typedef __attribute__((ext_vector_type(8))) unsigned short u16x8;

#define LDS_STRIDE 72   // reg-staged kernels

__device__ __forceinline__ unsigned short f2bf(float f) {
    __hip_bfloat16 h = __float2bfloat16(f);
    unsigned short u; __builtin_memcpy(&u, &h, 2); return u;
}
__device__ __forceinline__ float bf2f(unsigned short u) {
    union { unsigned u; float f; } v; v.u = ((unsigned)u) << 16; return v.f;
}
__device__ __forceinline__ float fast_sigmoid(float x) { return 1.f / (1.f + __expf(-x)); }
__device__ __forceinline__ float fast_tanh(float x)    { return 1.f - 2.f / (__expf(2.f * x) + 1.f); }

#define GLOAD_LDS16(gp, lp) __builtin_amdgcn_global_load_lds( \
    (const __attribute__((address_space(1))) void*)(gp), \
    (__attribute__((address_space(3))) void*)(lp), 16, 0, 0)

// ===========================================================================
// 8-phase 256x256 e-GEMM — UNCHANGED from r9/r11 (verified, 195 us, 705 TF).
// ===========================================================================

#define STA(LB, HF, PTR) do { \
    GLOAD_LDS16((PTR), &AL[LB][HF][ldsrow][0]); \
    GLOAD_LDS16((PTR) + 65536, &AL[LB][HF][64 + ldsrow][0]); \
} while (0)

#define STB(LB, HF, PTR) do { \
    GLOAD_LDS16((PTR), &BL[LB][HF][ldsrow][0]); \
    GLOAD_LDS16((PTR) + 65536, &BL[LB][HF][64 + ldsrow][0]); \
} while (0)

#define LDA(DST, BUF, MH, KS) do { \
    const int c_ = ((KS)*32 + fg*8) ^ swzr; \
    _Pragma("unroll") \
    for (int mi = 0; mi < 4; ++mi) \
        DST[mi] = *(const bf16x8*)&AL[BUF][wr][(MH)*64 + mi*16 + fr][c_]; \
} while (0)

#define LDB(DST, BUF, KS) do { \
    const int c_ = ((KS)*32 + fg*8) ^ swzr; \
    _Pragma("unroll") \
    for (int ni = 0; ni < 4; ++ni) \
        DST[ni] = *(const bf16x8*)&BL[BUF][bh][br0 + ni*16 + fr][c_]; \
} while (0)

#define MM(AV, BV, MH) do { \
    _Pragma("unroll") \
    for (int mi = 0; mi < 4; ++mi) \
        _Pragma("unroll") \
        for (int ni = 0; ni < 4; ++ni) \
            acc[(MH)*4 + mi][ni] = __builtin_amdgcn_mfma_f32_16x16x32_bf16( \
                AV[mi], BV[ni], acc[(MH)*4 + mi][ni], 0, 0, 0); \
} while (0)

#define SP1 __builtin_amdgcn_s_setprio(1)
#define SP0 __builtin_amdgcn_s_setprio(0)
#define BAR asm volatile("s_barrier" ::: "memory")
#define VMC8 asm volatile("s_waitcnt vmcnt(8)" ::: "memory")
#define VMC0 asm volatile("s_waitcnt vmcnt(0)" ::: "memory")

__global__ __launch_bounds__(512, 1)
void gemm8p_e(const unsigned short* __restrict__ Ag, const unsigned short* __restrict__ Bg,
              const float* __restrict__ hproj, const float* __restrict__ wscore,
              float* __restrict__ epart)
{
    const int tid = threadIdx.x;
    const int lane = tid & 63, wid = tid >> 6;
    const int fr = lane & 15, fg = lane >> 4;
    const int wr = wid >> 2;
    const int wc = wid & 3;
    const int bh = wc >> 1, br0 = (wc & 1) * 64;

    const int cpx = (int)gridDim.x >> 3;
    const int swz = ((int)blockIdx.x & 7) * cpx + ((int)blockIdx.x >> 3);
    const int mb = swz >> 2, nb = swz & 3;
    const int m0 = mb << 8, n0 = nb << 8;

    __shared__ unsigned short AL[3][2][128][64];
    __shared__ unsigned short BL[2][2][128][64];

    const int srow = lane >> 3;
    const int scol = ((lane & 7) ^ srow) << 3;
    const int swzr = (fr & 7) << 3;
    const int ldsrow = wid * 8;

    const unsigned short* pA0 = Ag + (size_t)(m0 + ldsrow + srow) * 1024 + scol;
    const unsigned short* pA1 = pA0 + (size_t)128 * 1024;
    const unsigned short* pB0 = Bg + (size_t)(n0 + ldsrow + srow) * 1024 + scol;
    const unsigned short* pB1 = pB0 + (size_t)128 * 1024;

    f32x4 acc[8][4];
#pragma unroll
    for (int i = 0; i < 8; ++i)
#pragma unroll
        for (int j = 0; j < 4; ++j) acc[i][j] = (f32x4){0.f, 0.f, 0.f, 0.f};
    bf16x8 avA[4], avB[4], bvA[4], bvB[4];

    STA(0, 0, pA0);      STA(0, 1, pA1);
    STB(0, 0, pB0);      STB(0, 1, pB1);
    STA(1, 0, pA0 + 64); STA(1, 1, pA1 + 64);
    STB(1, 0, pB0 + 64); STB(1, 1, pB1 + 64);
    VMC8;
    BAR;

#pragma unroll
    for (int t = 0; t < 16; t += 2) {
        const int tof = t * 64;
        const int a0 = t % 3, a1 = (t + 1) % 3, a2 = (t + 2) % 3, a3 = (t + 3) % 3;
        LDB(bvA, 0, 0); LDA(avA, a0, 0, 0);
        SP1; MM(avA, bvA, 0); SP0;
        LDB(bvB, 0, 1); LDA(avB, a0, 0, 1);
        if (t + 2 < 16) STA(a2, 0, pA0 + tof + 128);
        BAR;
        SP1; MM(avB, bvB, 0); SP0;
        LDA(avA, a0, 1, 0);
        if (t + 2 < 16) STA(a2, 1, pA1 + tof + 128);
        BAR;
        SP1; MM(avA, bvA, 1); SP0;
        LDA(avB, a0, 1, 1);
        if (t + 2 < 16) STB(0, 0, pB0 + tof + 128);
        BAR;
        SP1; MM(avB, bvB, 1); SP0;
        if (t + 2 < 16) { STB(0, 1, pB1 + tof + 128); VMC8; } else { VMC0; }
        BAR;
        LDB(bvA, 1, 0); LDA(avA, a1, 0, 0);
        SP1; MM(avA, bvA, 0); SP0;
        LDB(bvB, 1, 1); LDA(avB, a1, 0, 1);
        if (t + 3 < 16) STA(a3, 0, pA0 + tof + 192);
        BAR;
        SP1; MM(avB, bvB, 0); SP0;
        LDA(avA, a1, 1, 0);
        if (t + 3 < 16) STA(a3, 1, pA1 + tof + 192);
        BAR;
        SP1; MM(avA, bvA, 1); SP0;
        LDA(avB, a1, 1, 1);
        if (t + 3 < 16) STB(1, 0, pB0 + tof + 192);
        BAR;
        SP1; MM(avB, bvB, 1); SP0;
        if (t + 3 < 16) { STB(1, 1, pB1 + tof + 192); VMC8; }
        BAR;
    }

    float wsv[4];
#pragma unroll
    for (int ni = 0; ni < 4; ++ni) wsv[ni] = wscore[n0 + wc * 64 + ni * 16 + fr];
#pragma unroll
    for (int mi = 0; mi < 8; ++mi)
#pragma unroll
        for (int r = 0; r < 4; ++r) {
            const int bb = wr * 128 + mi * 16 + fg * 4 + r;
            const float* hp = hproj + (size_t)bb * 1024 + n0 + wc * 64 + fr;
            float s = 0.f;
#pragma unroll
            for (int ni = 0; ni < 4; ++ni)
                s += fast_tanh(acc[mi][ni][r] + hp[ni * 16]) * wsv[ni];
            s += __shfl_xor(s, 1); s += __shfl_xor(s, 2);
            s += __shfl_xor(s, 4); s += __shfl_xor(s, 8);
            if (fr == 0) epart[((size_t)bb * 256 + mb) * 16 + nb * 4 + wc] = s;
        }
}

// ---------------------------------------------------------------------------
// h2 body (device): C = h0 @ [W_h2h ; W_hh]^T + bias, one 128x128 tile/block.
// ---------------------------------------------------------------------------
__device__ void h2_body(char* smem, int blk, const float* __restrict__ h0,
                        const float* __restrict__ Wh2h, const float* __restrict__ Whh,
                        const float* __restrict__ bh2h, const float* __restrict__ bhh,
                        float* __restrict__ hproj, float* __restrict__ gh)
{
    const int mb = blk & 1;
    const int nbg = blk >> 1;
    const float* Bf; const float* bias; float* Cout; int Nst; int n0;
    if (nbg < 8) { Bf = Wh2h; bias = bh2h; Cout = hproj; Nst = 1024; n0 = nbg << 7; }
    else         { Bf = Whh;  bias = bhh;  Cout = gh;    Nst = 3072; n0 = (nbg - 8) << 7; }

    const int m0 = mb << 7;
    const int tid = threadIdx.x;
    const int lane = tid & 63, wid = tid >> 6;
    const int fr = lane & 15, fg = lane >> 4;
    const int srow = tid >> 1, shalf = (tid & 1) * 32;

    typedef unsigned short (*tile_t)[128][LDS_STRIDE];
    tile_t As = (tile_t)smem;
    tile_t Bs = (tile_t)(smem + 2 * 128 * LDS_STRIDE * 2);

    f32x4 acc[2][8];
#pragma unroll
    for (int i = 0; i < 2; ++i)
#pragma unroll
        for (int j = 0; j < 8; ++j) acc[i][j] = (f32x4){0.f, 0.f, 0.f, 0.f};

    float a_f[32], b_f[32];

    auto loadA = [&](int kt) {
        size_t base = (size_t)(m0 + srow) * 1024 + (size_t)kt * 64 + shalf;
#pragma unroll
        for (int j = 0; j < 8; ++j) *(f32x4*)&a_f[j * 4] = *(const f32x4*)(h0 + base + j * 4);
    };
    auto loadB = [&](int kt) {
        size_t base = (size_t)(n0 + srow) * 1024 + (size_t)kt * 64 + shalf;
#pragma unroll
        for (int j = 0; j < 8; ++j) *(f32x4*)&b_f[j * 4] = *(const f32x4*)(Bf + base + j * 4);
    };
    auto storeA = [&](int buf) {
        unsigned short t[32];
#pragma unroll
        for (int j = 0; j < 32; ++j) t[j] = f2bf(a_f[j]);
#pragma unroll
        for (int j = 0; j < 4; ++j) *(i32x4*)&As[buf][srow][shalf + j * 8] = *(i32x4*)&t[j * 8];
    };
    auto storeB = [&](int buf) {
        unsigned short t[32];
#pragma unroll
        for (int j = 0; j < 32; ++j) t[j] = f2bf(b_f[j]);
#pragma unroll
        for (int j = 0; j < 4; ++j) *(i32x4*)&Bs[buf][srow][shalf + j * 8] = *(i32x4*)&t[j * 8];
    };

    loadA(0); loadB(0);
    storeA(0); storeB(0);
    __syncthreads();

    for (int kt = 0; kt < 16; ++kt) {
        const int cur = kt & 1;
        if (kt + 1 < 16) { loadA(kt + 1); loadB(kt + 1); }
#pragma unroll
        for (int ks = 0; ks < 2; ++ks) {
            bf16x8 av[2], bv[8];
#pragma unroll
            for (int mi = 0; mi < 2; ++mi)
                av[mi] = *(const bf16x8*)&As[cur][wid * 32 + mi * 16 + fr][ks * 32 + fg * 8];
#pragma unroll
            for (int ni = 0; ni < 8; ++ni)
                bv[ni] = *(const bf16x8*)&Bs[cur][ni * 16 + fr][ks * 32 + fg * 8];
#pragma unroll
            for (int mi = 0; mi < 2; ++mi)
#pragma unroll
                for (int ni = 0; ni < 8; ++ni)
                    acc[mi][ni] = __builtin_amdgcn_mfma_f32_16x16x32_bf16(av[mi], bv[ni], acc[mi][ni], 0, 0, 0);
        }
        if (kt + 1 < 16) { storeA(cur ^ 1); storeB(cur ^ 1); }
        __syncthreads();
    }

#pragma unroll
    for (int mi = 0; mi < 2; ++mi)
#pragma unroll
        for (int r = 0; r < 4; ++r) {
            const int m = m0 + wid * 32 + mi * 16 + fg * 4 + r;
#pragma unroll
            for (int ni = 0; ni < 8; ++ni) {
                const int col = n0 + ni * 16 + fr;
                Cout[(size_t)m * Nst + col] = acc[mi][ni][r] + bias[col];
            }
        }
}

// ---------------------------------------------------------------------------
// FUSED prep + h2: blocks 0..63 -> h2 GEMM; blocks 64.. -> enc/W_i2h/emb prep.
// ---------------------------------------------------------------------------
__global__ __launch_bounds__(256, 2)
void prep_h2(const float* __restrict__ enc, unsigned short* __restrict__ encB,
             const float* __restrict__ Wi2h, unsigned short* __restrict__ WiB,
             const float* __restrict__ emb, const int* __restrict__ tokens,
             unsigned short* __restrict__ xB,
             const float* __restrict__ h0,
             const float* __restrict__ Wh2h, const float* __restrict__ Whh,
             const float* __restrict__ bh2h, const float* __restrict__ bhh,
             float* __restrict__ hproj, float* __restrict__ gh)
{
    extern __shared__ char smem[];
    if (blockIdx.x < 64) {
        h2_body(smem, blockIdx.x, h0, Wh2h, Whh, bh2h, bhh, hproj, gh);
        return;
    }
    const int ENC4 = 16777216, WI4 = 262144, EMB4 = 65536;
    const int total = ENC4 + WI4 + EMB4;
    const int stride = ((int)gridDim.x - 64) * 256;
    for (int i = ((int)blockIdx.x - 64) * 256 + (int)threadIdx.x; i < total; i += stride) {
        f32x4 v; unsigned short* dst;
        if (i < ENC4) {
            v = *(const f32x4*)(enc + (size_t)i * 4);
            dst = encB + (size_t)i * 4;
        } else if (i < ENC4 + WI4) {
            int j = i - ENC4;
            v = *(const f32x4*)(Wi2h + (size_t)j * 4);
            dst = WiB + (size_t)j * 4;
        } else {
            int j = i - ENC4 - WI4;
            int b = j >> 8, h4 = j & 255;
            v = *(const f32x4*)(emb + (size_t)tokens[b] * 1024 + h4 * 4);
            dst = xB + (size_t)b * 2048 + 1024 + h4 * 4;
        }
        u16x4 o;
#pragma unroll
        for (int j = 0; j < 4; ++j) o[j] = f2bf(v[j]);
        *(u16x4*)dst = o;
    }
}

// standalone h2 (fallback path)
__global__ __launch_bounds__(256, 2)
void gemm_h2(const float* __restrict__ h0,
             const float* __restrict__ Wh2h, const float* __restrict__ Whh,
             const float* __restrict__ bh2h, const float* __restrict__ bhh,
             float* __restrict__ hproj, float* __restrict__ gh)
{
    extern __shared__ char smem[];
    h2_body(smem, blockIdx.x, h0, Wh2h, Whh, bh2h, bhh, hproj, gh);
}

// ---------------------------------------------------------------------------
// FUSED softmax + context partials: grid (256 b, 4 tc) x 256 thr.
// Each block recomputes the full softmax for batch b from epart (16 KB,
// L2-hot; math identical to verified softmax_alpha pw=16); block tc==0 also
// writes the alpha output row. Then the block accumulates its 64-t context
// chunk from bf16 enc into pc (layout identical to ctx_part_bf).
// ---------------------------------------------------------------------------
__global__ __launch_bounds__(256) void sm_ctx(const float* __restrict__ epart,
                                              float* __restrict__ alpha,
                                              const unsigned short* __restrict__ encB,
                                              float* __restrict__ pc)
{
    const int b = blockIdx.x, tc = blockIdx.y;
    const int t = threadIdx.x;
    const int lane = t & 63, wv = t >> 6;

    // ---- softmax over all 256 t (thread t owns time t) ----
    const float* ep = epart + ((size_t)b * 256 + t) * 16;
    float s = 0.f;
#pragma unroll
    for (int j = 0; j < 16; ++j) s += ep[j];
    __shared__ float rmax[4], rsum[4];
    float mx = s;
#pragma unroll
    for (int d = 1; d < 64; d <<= 1) mx = fmaxf(mx, __shfl_xor(mx, d));
    if (lane == 0) rmax[wv] = mx;
    __syncthreads();
    mx = fmaxf(fmaxf(rmax[0], rmax[1]), fmaxf(rmax[2], rmax[3]));
    float p = __expf(s - mx);
    float sm = p;
#pragma unroll
    for (int d = 1; d < 64; d <<= 1) sm += __shfl_xor(sm, d);
    if (lane == 0) rsum[wv] = sm;
    __syncthreads();
    sm = rsum[0] + rsum[1] + rsum[2] + rsum[3];
    const float a = p / sm;
    if (tc == 0) alpha[(size_t)b * 256 + t] = a;

    __shared__ float al[256];
    al[t] = a;
    __syncthreads();

    // ---- context partial for t in [tc*64, tc*64+64) ----
    if (t < 128) {
        const int h8 = t;
        float acc[8];
#pragma unroll
        for (int j = 0; j < 8; ++j) acc[j] = 0.f;
#pragma unroll 4
        for (int i = 0; i < 64; ++i) {
            const int tt = tc * 64 + i;
            const float av = al[tt];
            u16x8 e = *(const u16x8*)(encB + ((size_t)tt * 256 + b) * 1024 + h8 * 8);
#pragma unroll
            for (int j = 0; j < 8; ++j) acc[j] += bf2f(e[j]) * av;
        }
        float* d = pc + ((size_t)tc * 256 + b) * 1024 + h8 * 8;
        *(f32x4*)d = *(f32x4*)&acc[0];
        *(f32x4*)(d + 4) = *(f32x4*)&acc[4];
    }
}

// ---------------------------------------------------------------------------
// gi GEMM with 8-way K-split: gip[s][256][3072] = xB[:, s*256:(s+1)*256] @
// W_ih[:, s*256:(s+1)*256]^T. 384 blocks. No bias (added in gru8).
// ---------------------------------------------------------------------------
__global__ __launch_bounds__(256, 2)
void gemm_gi(const unsigned short* __restrict__ xB, const float* __restrict__ Wih,
             float* __restrict__ gip)
{
    const int s = blockIdx.x / 48;
    const int blk = blockIdx.x % 48;
    const int mb = blk & 1, nb = blk >> 1;
    const int m0 = mb << 7, n0 = nb << 7;
    const int kbase = s * 256;
    const int tid = threadIdx.x;
    const int lane = tid & 63, wid = tid >> 6;
    const int fr = lane & 15, fg = lane >> 4;
    const int srow = tid >> 1, shalf = (tid & 1) * 32;

    extern __shared__ char smem[];
    typedef unsigned short (*tile_t)[128][LDS_STRIDE];
    tile_t As = (tile_t)smem;
    tile_t Bs = (tile_t)(smem + 2 * 128 * LDS_STRIDE * 2);

    f32x4 acc[2][8];
#pragma unroll
    for (int i = 0; i < 2; ++i)
#pragma unroll
        for (int j = 0; j < 8; ++j) acc[i][j] = (f32x4){0.f, 0.f, 0.f, 0.f};

    unsigned short a_b[32]; float b_f[32];

    auto loadA = [&](int kt) {
        size_t base = (size_t)(m0 + srow) * 2048 + kbase + (size_t)kt * 64 + shalf;
#pragma unroll
        for (int j = 0; j < 4; ++j) *(i32x4*)&a_b[j * 8] = *(const i32x4*)(xB + base + j * 8);
    };
    auto loadB = [&](int kt) {
        size_t base = (size_t)(n0 + srow) * 2048 + kbase + (size_t)kt * 64 + shalf;
#pragma unroll
        for (int j = 0; j < 8; ++j) *(f32x4*)&b_f[j * 4] = *(const f32x4*)(Wih + base + j * 4);
    };
    auto storeA = [&](int buf) {
#pragma unroll
        for (int j = 0; j < 4; ++j) *(i32x4*)&As[buf][srow][shalf + j * 8] = *(i32x4*)&a_b[j * 8];
    };
    auto storeB = [&](int buf) {
        unsigned short t[32];
#pragma unroll
        for (int j = 0; j < 32; ++j) t[j] = f2bf(b_f[j]);
#pragma unroll
        for (int j = 0; j < 4; ++j) *(i32x4*)&Bs[buf][srow][shalf + j * 8] = *(i32x4*)&t[j * 8];
    };

    loadA(0); loadB(0);
    storeA(0); storeB(0);
    __syncthreads();

    for (int kt = 0; kt < 4; ++kt) {
        const int cur = kt & 1;
        if (kt + 1 < 4) { loadA(kt + 1); loadB(kt + 1); }
#pragma unroll
        for (int ks = 0; ks < 2; ++ks) {
            bf16x8 av[2], bv[8];
#pragma unroll
            for (int mi = 0; mi < 2; ++mi)
                av[mi] = *(const bf16x8*)&As[cur][wid * 32 + mi * 16 + fr][ks * 32 + fg * 8];
#pragma unroll
            for (int ni = 0; ni < 8; ++ni)
                bv[ni] = *(const bf16x8*)&Bs[cur][ni * 16 + fr][ks * 32 + fg * 8];
#pragma unroll
            for (int mi = 0; mi < 2; ++mi)
#pragma unroll
                for (int ni = 0; ni < 8; ++ni)
                    acc[mi][ni] = __builtin_amdgcn_mfma_f32_16x16x32_bf16(av[mi], bv[ni], acc[mi][ni], 0, 0, 0);
        }
        if (kt + 1 < 4) { storeA(cur ^ 1); storeB(cur ^ 1); }
        __syncthreads();
    }

    float* Cs = gip + (size_t)s * 256 * 3072;
#pragma unroll
    for (int mi = 0; mi < 2; ++mi)
#pragma unroll
        for (int r = 0; r < 4; ++r) {
            const int m = m0 + wid * 32 + mi * 16 + fg * 4 + r;
#pragma unroll
            for (int ni = 0; ni < 8; ++ni) {
                const int col = n0 + ni * 16 + fr;
                Cs[(size_t)m * 3072 + col] = acc[mi][ni][r];
            }
        }
}

// ---------------------------------------------------------------------------
// Reg-staged GEMM — fallback e-GEMM (EPI1), gi fallback (EPI0), logits (EPI2).
// ---------------------------------------------------------------------------
template<int EPI, bool ABF, bool BBF>
__global__ __launch_bounds__(256, 2)
void gemm_rs(const void* __restrict__ Agv, const void* __restrict__ Bgv,
             const float* __restrict__ bias, float* __restrict__ Cout,
             unsigned short* __restrict__ CoutB,
             const float* __restrict__ hproj, const float* __restrict__ wscore,
             float* __restrict__ epart, float* __restrict__ lsepart,
             int M, int N, int K)
{
    const int nbn = N >> 7;
    const int nmb = M >> 7;
    int mb, nb;
    if (EPI == 1) {
        int cpx = gridDim.x >> 3;
        int bp = (blockIdx.x & 7) * cpx + (blockIdx.x >> 3);
        mb = bp / nbn; nb = bp % nbn;
    } else {
        mb = blockIdx.x % nmb; nb = blockIdx.x / nmb;
    }
    const int m0 = mb << 7, n0 = nb << 7;
    const int tid = threadIdx.x;
    const int lane = tid & 63, wid = tid >> 6;
    const int fr = lane & 15, fg = lane >> 4;
    const int srow = tid >> 1, shalf = (tid & 1) * 32;

    extern __shared__ char smem[];
    typedef unsigned short (*tile_t)[128][LDS_STRIDE];
    tile_t As = (tile_t)smem;
    tile_t Bs = (tile_t)(smem + 2 * 128 * LDS_STRIDE * 2);

    const float* Af = (const float*)Agv;
    const unsigned short* Ab = (const unsigned short*)Agv;
    const float* Bf = (const float*)Bgv;
    const unsigned short* Bb = (const unsigned short*)Bgv;

    f32x4 acc[2][8];
#pragma unroll
    for (int i = 0; i < 2; ++i)
#pragma unroll
        for (int j = 0; j < 8; ++j) acc[i][j] = (f32x4){0.f, 0.f, 0.f, 0.f};

    float a_f[32]; unsigned short a_b[32];
    float b_f[32]; unsigned short b_b[32];

    auto loadA = [&](int kt) {
        size_t base = (size_t)(m0 + srow) * K + (size_t)kt * 64 + shalf;
        if (ABF) {
#pragma unroll
            for (int j = 0; j < 4; ++j) *(i32x4*)&a_b[j * 8] = *(const i32x4*)(Ab + base + j * 8);
        } else {
#pragma unroll
            for (int j = 0; j < 8; ++j) *(f32x4*)&a_f[j * 4] = *(const f32x4*)(Af + base + j * 4);
        }
    };
    auto loadB = [&](int kt) {
        size_t base = (size_t)(n0 + srow) * K + (size_t)kt * 64 + shalf;
        if (BBF) {
#pragma unroll
            for (int j = 0; j < 4; ++j) *(i32x4*)&b_b[j * 8] = *(const i32x4*)(Bb + base + j * 8);
        } else {
#pragma unroll
            for (int j = 0; j < 8; ++j) *(f32x4*)&b_f[j * 4] = *(const f32x4*)(Bf + base + j * 4);
        }
    };
    auto storeA = [&](int buf) {
        unsigned short tA[32];
        if (ABF) {
#pragma unroll
            for (int j = 0; j < 32; ++j) tA[j] = a_b[j];
        } else {
#pragma unroll
            for (int j = 0; j < 32; ++j) tA[j] = f2bf(a_f[j]);
        }
#pragma unroll
        for (int j = 0; j < 4; ++j) *(i32x4*)&As[buf][srow][shalf + j * 8] = *(i32x4*)&tA[j * 8];
    };
    auto storeB = [&](int buf) {
        unsigned short tB[32];
        if (BBF) {
#pragma unroll
            for (int j = 0; j < 32; ++j) tB[j] = b_b[j];
        } else {
#pragma unroll
            for (int j = 0; j < 32; ++j) tB[j] = f2bf(b_f[j]);
        }
#pragma unroll
        for (int j = 0; j < 4; ++j) *(i32x4*)&Bs[buf][srow][shalf + j * 8] = *(i32x4*)&tB[j * 8];
    };

    const int nkt = K >> 6;

    loadA(0); loadB(0);
    storeA(0); storeB(0);
    __syncthreads();

    for (int kt = 0; kt < nkt; ++kt) {
        const int cur = kt & 1;
        if (kt + 1 < nkt) { loadA(kt + 1); loadB(kt + 1); }
#pragma unroll
        for (int ks = 0; ks < 2; ++ks) {
            bf16x8 av[2], bv[8];
#pragma unroll
            for (int mi = 0; mi < 2; ++mi)
                av[mi] = *(const bf16x8*)&As[cur][wid * 32 + mi * 16 + fr][ks * 32 + fg * 8];
#pragma unroll
            for (int ni = 0; ni < 8; ++ni)
                bv[ni] = *(const bf16x8*)&Bs[cur][ni * 16 + fr][ks * 32 + fg * 8];
#pragma unroll
            for (int mi = 0; mi < 2; ++mi)
#pragma unroll
                for (int ni = 0; ni < 8; ++ni)
                    acc[mi][ni] = __builtin_amdgcn_mfma_f32_16x16x32_bf16(av[mi], bv[ni], acc[mi][ni], 0, 0, 0);
        }
        if (kt + 1 < nkt) { storeA(cur ^ 1); storeB(cur ^ 1); }
        __syncthreads();
    }

    if (EPI == 0) {
#pragma unroll
        for (int mi = 0; mi < 2; ++mi)
#pragma unroll
            for (int r = 0; r < 4; ++r) {
                const int m = m0 + wid * 32 + mi * 16 + fg * 4 + r;
#pragma unroll
                for (int ni = 0; ni < 8; ++ni) {
                    const int col = n0 + ni * 16 + fr;
                    Cout[(size_t)m * N + col] = acc[mi][ni][r] + bias[col];
                }
            }
    } else if (EPI == 1) {
        float wsv[8];
#pragma unroll
        for (int ni = 0; ni < 8; ++ni) wsv[ni] = wscore[n0 + ni * 16 + fr];
#pragma unroll
        for (int mi = 0; mi < 2; ++mi)
#pragma unroll
            for (int r = 0; r < 4; ++r) {
                const int m = m0 + wid * 32 + mi * 16 + fg * 4 + r;
                const int bb = m & 255, tt = m >> 8;
                const float* hp = hproj + (size_t)bb * 1024 + n0 + fr;
                float s = 0.f;
#pragma unroll
                for (int ni = 0; ni < 8; ++ni)
                    s += fast_tanh(acc[mi][ni][r] + hp[ni * 16]) * wsv[ni];
                s += __shfl_xor(s, 1); s += __shfl_xor(s, 2);
                s += __shfl_xor(s, 4); s += __shfl_xor(s, 8);
                if (fr == 0) epart[((size_t)bb * 256 + tt) * 8 + nb] = s;
            }
    } else {  // EPI 2: bf16 logits + (max,sumexp) partials
#pragma unroll
        for (int mi = 0; mi < 2; ++mi)
#pragma unroll
            for (int r = 0; r < 4; ++r) {
                const int m = m0 + wid * 32 + mi * 16 + fg * 4 + r;
                float vv[8];
                float mx = -3.4e38f;
#pragma unroll
                for (int ni = 0; ni < 8; ++ni) {
                    const int col = n0 + ni * 16 + fr;
                    vv[ni] = acc[mi][ni][r] + bias[col];
                    CoutB[(size_t)m * N + col] = f2bf(vv[ni]);
                    mx = fmaxf(mx, vv[ni]);
                }
                mx = fmaxf(mx, __shfl_xor(mx, 1));
                mx = fmaxf(mx, __shfl_xor(mx, 2));
                mx = fmaxf(mx, __shfl_xor(mx, 4));
                mx = fmaxf(mx, __shfl_xor(mx, 8));
                float se = 0.f;
#pragma unroll
                for (int ni = 0; ni < 8; ++ni) se += __expf(vv[ni] - mx);
                se += __shfl_xor(se, 1); se += __shfl_xor(se, 2);
                se += __shfl_xor(se, 4); se += __shfl_xor(se, 8);
                if (fr == 0) {
                    lsepart[((size_t)m * nbn + nb) * 2]     = mx;
                    lsepart[((size_t)m * nbn + nb) * 2 + 1] = se;
                }
            }
    }
}

// fallback prep: W_i2h conv + emb gather only
__global__ void prep_kernel(const float* __restrict__ Wi2h, unsigned short* __restrict__ WiB,
                            const float* __restrict__ emb, const int* __restrict__ tokens,
                            unsigned short* __restrict__ xB)
{
    int i = blockIdx.x * 256 + threadIdx.x;
    if (i < 262144) {
        f32x4 v = *(const f32x4*)(Wi2h + (size_t)i * 4);
        u16x4 o;
#pragma unroll
        for (int j = 0; j < 4; ++j) o[j] = f2bf(v[j]);
        *(u16x4*)(WiB + (size_t)i * 4) = o;
    } else {
        int j = i - 262144;
        int b = j >> 8, h4 = j & 255;
        int tok = tokens[b];
        f32x4 v = *(const f32x4*)(emb + (size_t)tok * 1024 + h4 * 4);
        u16x4 o;
#pragma unroll
        for (int jj = 0; jj < 4; ++jj) o[jj] = f2bf(v[jj]);
        *(u16x4*)(xB + (size_t)b * 2048 + 1024 + h4 * 4) = o;
    }
}

// fallback softmax (pw variable)
__global__ __launch_bounds__(256) void softmax_alpha(const float* __restrict__ epart,
                                                     float* __restrict__ alpha, int pw)
{
    const int b = blockIdx.x, t = threadIdx.x;
    const int lane = t & 63, w = t >> 6;
    const float* ep = epart + ((size_t)b * 256 + t) * pw;
    float s = 0.f;
    for (int j = 0; j < pw; ++j) s += ep[j];
    __shared__ float rmax[4], rsum[4];
    float mx = s;
#pragma unroll
    for (int d = 1; d < 64; d <<= 1) mx = fmaxf(mx, __shfl_xor(mx, d));
    if (lane == 0) rmax[w] = mx;
    __syncthreads();
    mx = fmaxf(fmaxf(rmax[0], rmax[1]), fmaxf(rmax[2], rmax[3]));
    float p = __expf(s - mx);
    float sm = p;
#pragma unroll
    for (int d = 1; d < 64; d <<= 1) sm += __shfl_xor(sm, d);
    if (lane == 0) rsum[w] = sm;
    __syncthreads();
    sm = rsum[0] + rsum[1] + rsum[2] + rsum[3];
    alpha[(size_t)b * 256 + t] = p / sm;
}

// fallback f32 ctx_part
__global__ __launch_bounds__(256) void ctx_part(const float* __restrict__ alpha,
                                                const float* __restrict__ enc,
                                                float* __restrict__ pc)
{
    const int b = blockIdx.x, tc = blockIdx.y;
    const int h4 = threadIdx.x;
    const float* al = alpha + (size_t)b * 256 + tc * 64;
    f32x4 acc = {0.f, 0.f, 0.f, 0.f};
#pragma unroll 4
    for (int i = 0; i < 64; ++i) {
        float a = al[i];
        f32x4 e = *(const f32x4*)(enc + ((size_t)(tc * 64 + i) * 256 + b) * 1024 + h4 * 4);
        acc += e * a;
    }
    *(f32x4*)(pc + ((size_t)tc * 256 + b) * 1024 + h4 * 4) = acc;
}

// reduce context partials -> x_bf16[:,0:1024]
__global__ void ctx_fin(const float* __restrict__ pc, unsigned short* __restrict__ xB)
{
    const int b = blockIdx.x, h4 = threadIdx.x;
    f32x4 c = {0.f, 0.f, 0.f, 0.f};
#pragma unroll
    for (int tc = 0; tc < 4; ++tc)
        c += *(const f32x4*)(pc + ((size_t)tc * 256 + b) * 1024 + h4 * 4);
    u16x4 o;
#pragma unroll
    for (int j = 0; j < 4; ++j) o[j] = f2bf(c[j]);
    *(u16x4*)(xB + (size_t)b * 2048 + h4 * 4) = o;
}

// GRU elementwise with 8-way gi split sum + b_ih (PyTorch gate order r,z,n)
__global__ void gru8_kernel(const float* __restrict__ gip, const float* __restrict__ gh,
                            const float* __restrict__ bih, const float* __restrict__ h0,
                            float* __restrict__ hnew, unsigned short* __restrict__ hnB)
{
    int idx = blockIdx.x * 256 + threadIdx.x;
    int b = idx >> 10, h = idx & 1023;
    size_t gb = (size_t)b * 3072;
    const size_t S = (size_t)256 * 3072;
    float g0 = bih[h], g1 = bih[1024 + h], g2 = bih[2048 + h];
#pragma unroll
    for (int s = 0; s < 8; ++s) {
        g0 += gip[s * S + gb + h];
        g1 += gip[s * S + gb + 1024 + h];
        g2 += gip[s * S + gb + 2048 + h];
    }
    float r = fast_sigmoid(g0 + gh[gb + h]);
    float z = fast_sigmoid(g1 + gh[gb + 1024 + h]);
    float n = fast_tanh   (g2 + r * gh[gb + 2048 + h]);
    float hp = h0[idx];
    float hn = (1.f - z) * n + z * hp;
    hnew[idx] = hn;
    hnB[idx] = f2bf(hn);
}

// fallback GRU (single gi incl. bias)
__global__ void gru_kernel(const float* __restrict__ gi, const float* __restrict__ gh,
                           const float* __restrict__ h0, float* __restrict__ hnew,
                           unsigned short* __restrict__ hnB)
{
    int idx = blockIdx.x * 256 + threadIdx.x;
    int b = idx >> 10, h = idx & 1023;
    size_t gb = (size_t)b * 3072;
    float r = fast_sigmoid(gi[gb + h]        + gh[gb + h]);
    float z = fast_sigmoid(gi[gb + 1024 + h] + gh[gb + 1024 + h]);
    float n = fast_tanh   (gi[gb + 2048 + h] + r * gh[gb + 2048 + h]);
    float hp = h0[idx];
    float hn = (1.f - z) * n + z * hp;
    hnew[idx] = hn;
    hnB[idx] = f2bf(hn);
}

// fused lse reduce + log-softmax subtract: one block per row m.
__global__ __launch_bounds__(256) void lse_sub(const float* __restrict__ lsepart,
                                               const unsigned short* __restrict__ lgB,
                                               float* __restrict__ out)
{
    const int m = blockIdx.x, tid = threadIdx.x;
    const int lane = tid & 63, w = tid >> 6;
    float mx = -3.4e38f, s = 0.f;
    if (tid < 250) {
        mx = lsepart[((size_t)m * 250 + tid) * 2];
        s  = lsepart[((size_t)m * 250 + tid) * 2 + 1];
    }
#pragma unroll
    for (int d = 1; d < 64; d <<= 1) {
        float om = __shfl_xor(mx, d), os = __shfl_xor(s, d);
        float nm = fmaxf(mx, om);
        s = s * __expf(mx - nm) + os * __expf(om - nm);
        mx = nm;
    }
    __shared__ float smx[4], ssm[4];
    if (lane == 0) { smx[w] = mx; ssm[w] = s; }
    __syncthreads();
    float fm = smx[0], fs = ssm[0];
#pragma unroll
    for (int i = 1; i < 4; ++i) {
        float nm = fmaxf(fm, smx[i]);
        fs = fs * __expf(fm - nm) + ssm[i] * __expf(smx[i] - nm);
        fm = nm;
    }
    const float lse = fm + __logf(fs);
    const unsigned short* lrow = lgB + (size_t)m * 32000;
    float* orow = out + (size_t)m * 32000;
    for (int j = tid; j < 4000; j += 256) {
        u16x8 v = *(const u16x8*)(lrow + (size_t)j * 8);
        f32x4 o0, o1;
#pragma unroll
        for (int k = 0; k < 4; ++k) o0[k] = bf2f(v[k]) - lse;
#pragma unroll
        for (int k = 0; k < 4; ++k) o1[k] = bf2f(v[4 + k]) - lse;
        *(f32x4*)(orow + (size_t)j * 8) = o0;
        *(f32x4*)(orow + (size_t)j * 8 + 4) = o1;
    }
}

// fallback lse/lsub pair
__global__ void lse_reduce(const float* __restrict__ lsepart, float* __restrict__ lse, int nbn)
{
    const int m = blockIdx.x, l = threadIdx.x;
    float mx = -3.4e38f, s = 0.f;
    for (int p = l; p < nbn; p += 64) {
        float pm = lsepart[((size_t)m * nbn + p) * 2];
        float ps = lsepart[((size_t)m * nbn + p) * 2 + 1];
        float nm = fmaxf(mx, pm);
        s = s * __expf(mx - nm) + ps * __expf(pm - nm);
        mx = nm;
    }
#pragma unroll
    for (int d = 1; d < 64; d <<= 1) {
        float om = __shfl_xor(mx, d), os = __shfl_xor(s, d);
        float nm = fmaxf(mx, om);
        s = s * __expf(mx - nm) + os * __expf(om - nm);
        mx = nm;
    }
    if (l == 0) lse[m] = mx + __logf(s);
}

__global__ void lsub_bf(const unsigned short* __restrict__ lgB,
                        const float* __restrict__ lse, float* __restrict__ out)
{
    int f = blockIdx.x * 256 + threadIdx.x;
    float l = lse[f / 4000];
    u16x8 v = *(const u16x8*)(lgB + (size_t)f * 8);
    float* o = out + (size_t)f * 8;
    f32x4 o0, o1;
#pragma unroll
    for (int j = 0; j < 4; ++j) o0[j] = bf2f(v[j]) - l;
#pragma unroll
    for (int j = 0; j < 4; ++j) o1[j] = bf2f(v[4 + j]) - l;
    *(f32x4*)o = o0;
    *(f32x4*)(o + 4) = o1;
}

// ---------------------------------------------------------------------------
extern "C" void kernel_launch(void* const* d_in, const int* in_sizes, int n_in,
                              void* d_out, int out_size, void* d_ws, size_t ws_size,
                              hipStream_t stream)
{
    const int*   tokens  = (const int*)  d_in[0];
    const float* h0      = (const float*)d_in[1];
    const float* enc     = (const float*)d_in[2];
    const float* emb     = (const float*)d_in[3];
    const float* W_i2h   = (const float*)d_in[4];
    const float* W_h2h   = (const float*)d_in[5];
    const float* b_h2h   = (const float*)d_in[6];
    const float* w_score = (const float*)d_in[7];
    const float* W_ih    = (const float*)d_in[8];
    const float* b_ih    = (const float*)d_in[9];
    const float* W_hh    = (const float*)d_in[10];
    const float* b_hh    = (const float*)d_in[11];
    const float* W_out   = (const float*)d_in[12];
    const float* b_out   = (const float*)d_in[13];

    float* out   = (float*)d_out;
    float* hnew  = out + (size_t)256 * 32000;
    float* alpha = hnew + 256 * 1024;

    const size_t RS_LDS = 2u * 2u * 128u * LDS_STRIDE * 2u;  // 73728 B

    char* w = (char*)d_ws;
    const size_t NEED = (size_t)153 * (1 << 20);

    if (ws_size >= NEED) {
        unsigned short* encB  = (unsigned short*)(w);                           // 128 MB
        unsigned short* lgB   = (unsigned short*)(w);                           // 16.4 MB, overlays dead encB
        float* gip            = (float*)(w + (size_t)32 * (1 << 20));           // 24 MB [8][256][3072], overlays dead encB (disjoint from lgB)
        unsigned short* WiB   = (unsigned short*)(w + (size_t)128 * (1 << 20)); // 2 MB
        float* hproj          = (float*)(w + (size_t)130 * (1 << 20));          // 1 MB
        float* gh             = (float*)(w + (size_t)131 * (1 << 20));          // 3 MB
        float* epart          = (float*)(w + (size_t)134 * (1 << 20));          // 4 MB [b][t][16]
        float* pc             = (float*)(w + (size_t)138 * (1 << 20));          // 4 MB
        unsigned short* xB    = (unsigned short*)(w + (size_t)142 * (1 << 20)); // 1 MB
        unsigned short* hnB   = (unsigned short*)(w + (size_t)150 * (1 << 20)); // 0.5 MB
        float* lsepart        = (float*)(w + (size_t)151 * (1 << 20));          // 0.5 MB

        // prep (blocks 64..2111) + h2 GEMM (blocks 0..63) fused
        prep_h2<<<2112, 256, RS_LDS, stream>>>(enc, encB, W_i2h, WiB, emb, tokens, xB,
                                               h0, W_h2h, W_hh, b_h2h, b_hh, hproj, gh);
        gemm8p_e<<<1024, 512, 0, stream>>>(encB, WiB, hproj, w_score, epart);
        // fused softmax (+alpha output) + context partials
        sm_ctx<<<dim3(256, 4), 256, 0, stream>>>(epart, alpha, encB, pc);
        ctx_fin<<<256, 256, 0, stream>>>(pc, xB);
        // gi GEMM: 8-way K-split, 384 blocks. encB dead after sm_ctx; gip at
        // [32,56) MB inside dead encB, disjoint from xB/pc/lgB/epart.
        gemm_gi<<<384, 256, RS_LDS, stream>>>(xB, W_ih, gip);
        gru8_kernel<<<1024, 256, 0, stream>>>(gip, gh, b_ih, h0, hnew, hnB);
        // lgB overlays encB [0,16.4) MB; gip dead once gru8 completes
        gemm_rs<2, true, false><<<500, 256, RS_LDS, stream>>>(hnB, W_out, b_out, nullptr,
            lgB, nullptr, nullptr, nullptr, lsepart, 256, 32000, 1024);
        lse_sub<<<256, 256, 0, stream>>>(lsepart, lgB, out);
    } else {
        // fallback: reg-staged everywhere (ws >= 36 MB)
        unsigned short* WiB   = (unsigned short*)(w);
        float* hproj          = (float*)(w + (size_t)2  * (1 << 20));
        float* gh             = (float*)(w + (size_t)3  * (1 << 20));
        float* epart          = (float*)(w + (size_t)6  * (1 << 20));
        float* pc             = (float*)(w + (size_t)8  * (1 << 20));
        unsigned short* xB    = (unsigned short*)(w + (size_t)12 * (1 << 20));
        float* gi             = (float*)(w + (size_t)13 * (1 << 20));
        unsigned short* hnB   = (unsigned short*)(w + (size_t)16 * (1 << 20));
        float* lsepart        = (float*)(w + (size_t)17 * (1 << 20));
        float* lse            = (float*)(w + (size_t)18 * (1 << 20));
        unsigned short* lgB   = (unsigned short*)(w + (size_t)19 * (1 << 20));

        prep_kernel<<<1280, 256, 0, stream>>>(W_i2h, WiB, emb, tokens, xB);
        gemm_h2<<<64, 256, RS_LDS, stream>>>(h0, W_h2h, W_hh, b_h2h, b_hh, hproj, gh);
        gemm_rs<1, false, true><<<4096, 256, RS_LDS, stream>>>(enc, WiB, nullptr, nullptr,
            nullptr, hproj, w_score, epart, nullptr, 65536, 1024, 1024);
        softmax_alpha<<<256, 256, 0, stream>>>(epart, alpha, 8);
        ctx_part<<<dim3(256, 4), 256, 0, stream>>>(alpha, enc, pc);
        ctx_fin<<<256, 256, 0, stream>>>(pc, xB);
        gemm_rs<0, true, false><<<48, 256, RS_LDS, stream>>>(xB, W_ih, b_ih, gi,
            nullptr, nullptr, nullptr, nullptr, nullptr, 256, 3072, 2048);
        gru_kernel<<<1024, 256, 0, stream>>>(gi, gh, h0, hnew, hnB);
        gemm_rs<2, true, false><<<500, 256, RS_LDS, stream>>>(hnB, W_out, b_out, nullptr,
            lgB, nullptr, nullptr, nullptr, lsepart, 256, 32000, 1024);
        lse_reduce<<<256, 64, 0, stream>>>(lsepart, lse, 250);
        lsub_bf<<<4000, 256, 0, stream>>>(lgB, lse, out);
    }
}